// Round 11
// baseline (802.280 us; speedup 1.0000x reference)
//
#include <hip/hip_runtime.h>
#include <cstddef>

#define B_SZ 2
#define S_LEN 1024
#define NH 16
#define HD 64
#define DIM 1024
#define HID 2816
#define NVOCAB 32000

typedef __attribute__((ext_vector_type(8))) short short8;
typedef __attribute__((ext_vector_type(4))) short short4v;
typedef __attribute__((ext_vector_type(4))) float f32x4;
typedef __attribute__((ext_vector_type(4))) unsigned short u16x4;
typedef unsigned short u16;

#if __has_builtin(__builtin_amdgcn_mfma_f32_16x16x16_bf16)
#define MFMA_PV(a,b,c) __builtin_amdgcn_mfma_f32_16x16x16_bf16(a,b,c,0,0,0)
#else
#define MFMA_PV(a,b,c) __builtin_amdgcn_mfma_f32_16x16x16bf16_1k(a,b,c,0,0,0)
#endif

static __device__ __forceinline__ u16 f2bf(float f){
  unsigned u = __float_as_uint(f);
  u += 0x7FFFu + ((u >> 16) & 1u);   // RNE
  return (u16)(u >> 16);
}
static __device__ __forceinline__ float bf2f(unsigned u){
  return __uint_as_float(u << 16);
}

// XCD-aware bijective block remap (T1). Requires nwg % 8 == 0 (all our grids comply).
static __device__ __forceinline__ int xcdswz(int bid, int nwg){
  return (bid & 7) * (nwg >> 3) + (bid >> 3);
}

// async global->LDS, 16B per lane. LDS dest = wave-uniform base + lane*16 (linear).
static __device__ __forceinline__ void gload16(const void* g, void* l){
  __builtin_amdgcn_global_load_lds(
    (const __attribute__((address_space(1))) unsigned int*)g,
    (__attribute__((address_space(3))) unsigned int*)l, 16, 0, 0);
}

// ---------------- weight convert + transpose: f32 [K][N] -> bf16 [N][K] ----------------
static __device__ __forceinline__ void tr_body(u16 (*ld)[65],
    const float* __restrict__ in, u16* __restrict__ out, int K, int N)
{
  const int t = threadIdx.x;
  const int n0 = blockIdx.x * 64, k0 = blockIdx.y * 64;
  #pragma unroll
  for (int i = 0; i < 4; ++i){
    int idx = i*256 + t;
    int r = idx >> 4, c4 = (idx & 15) * 4;
    f32x4 v = *(const f32x4*)&in[(size_t)(k0 + r) * N + n0 + c4];
    ld[r][c4+0] = f2bf(v[0]); ld[r][c4+1] = f2bf(v[1]);
    ld[r][c4+2] = f2bf(v[2]); ld[r][c4+3] = f2bf(v[3]);
  }
  __syncthreads();
  #pragma unroll
  for (int i = 0; i < 4; ++i){
    int idx = i*256 + t;
    int c = idx >> 4, r4 = (idx & 15) * 4;
    u16x4 pk;
    pk[0]=ld[r4+0][c]; pk[1]=ld[r4+1][c]; pk[2]=ld[r4+2][c]; pk[3]=ld[r4+3][c];
    *(u16x4*)&out[(size_t)(n0 + c) * K + k0 + r4] = pk;
  }
}

__global__ __launch_bounds__(256) void transpose4_k(
    const float* __restrict__ i0, const float* __restrict__ i1,
    const float* __restrict__ i2, const float* __restrict__ i3,
    u16* __restrict__ o0, u16* __restrict__ o1, u16* __restrict__ o2, u16* __restrict__ o3)
{
  __shared__ u16 ld[64][65];
  int w = blockIdx.z >> 2, lyr = blockIdx.z & 3;
  const float* in = (w==0)?i0:(w==1)?i1:(w==2)?i2:i3;
  u16*      out = (w==0)?o0:(w==1)?o1:(w==2)?o2:o3;
  tr_body(ld, in + (size_t)lyr*DIM*DIM, out + (size_t)lyr*DIM*DIM, DIM, DIM);
}

__global__ __launch_bounds__(256) void transpose2_k(
    const float* __restrict__ i0, const float* __restrict__ i1,
    u16* __restrict__ o0, u16* __restrict__ o1)
{
  __shared__ u16 ld[64][65];
  int w = blockIdx.z >> 2, lyr = blockIdx.z & 3;
  const float* in = w ? i1 : i0;
  u16*      out = w ? o1 : o0;
  tr_body(ld, in + (size_t)lyr*DIM*HID, out + (size_t)lyr*DIM*HID, DIM, HID);
}

__global__ __launch_bounds__(256) void transpose1_k(
    const float* __restrict__ in, u16* __restrict__ out)
{
  __shared__ u16 ld[64][65];
  tr_body(ld, in + (size_t)blockIdx.z*HID*DIM, out + (size_t)blockIdx.z*HID*DIM, HID, DIM);
}

// ---------------- embedding gather ----------------
__global__ __launch_bounds__(256) void embed_k(const int* __restrict__ tok,
    const float* __restrict__ emb, float* __restrict__ h)
{
  int row = blockIdx.x;
  int t = tok[row];
  const f32x4* src = (const f32x4*)(emb + (size_t)t * DIM);
  f32x4* dst = (f32x4*)(h + (size_t)row * DIM);
  dst[threadIdx.x] = src[threadIdx.x];
}

// ---------------- RoPE cos/sin table ----------------
__global__ __launch_bounds__(256) void freqs_k(float* __restrict__ tab,
    const int* __restrict__ spp)
{
  int i = blockIdx.x * 256 + threadIdx.x;   // [0, S_LEN*32)
  int s = i >> 5, kk = i & 31;
  float inv = powf(10000.0f, -(float)kk * (1.0f/32.0f));
  float ang = (float)(*spp + s) * inv;
  tab[i*2]   = cosf(ang);
  tab[i*2+1] = sinf(ang);
}

// ---------------- RMSNorm -> bf16 ----------------
__global__ __launch_bounds__(256) void rmsnorm_k(const float* __restrict__ x,
    const float* __restrict__ w, u16* __restrict__ out)
{
  int row = blockIdx.x, t = threadIdx.x;
  const float* xr = x + (size_t)row * DIM;
  float v[4]; float ss = 0.f;
  #pragma unroll
  for (int i=0;i<4;i++){ v[i] = xr[t + 256*i]; ss += v[i]*v[i]; }
  #pragma unroll
  for (int o=1;o<64;o<<=1) ss += __shfl_xor(ss, o);
  __shared__ float red[4];
  if ((t & 63) == 0) red[t>>6] = ss;
  __syncthreads();
  float tot = red[0]+red[1]+red[2]+red[3];
  float rs = rsqrtf(tot * (1.0f/DIM) + 1e-6f);
  u16* orow = out + (size_t)row * DIM;
  #pragma unroll
  for (int i=0;i<4;i++) orow[t + 256*i] = f2bf(v[i]*rs*w[t+256*i]);
}

// RMSNorm of last-position rows -> f32
__global__ __launch_bounds__(256) void rmsnorm_last_k(const float* __restrict__ x,
    const float* __restrict__ w, float* __restrict__ out)
{
  int row = (blockIdx.x + 1) * S_LEN - 1;
  int t = threadIdx.x;
  const float* xr = x + (size_t)row * DIM;
  float v[4]; float ss = 0.f;
  #pragma unroll
  for (int i=0;i<4;i++){ v[i] = xr[t + 256*i]; ss += v[i]*v[i]; }
  #pragma unroll
  for (int o=1;o<64;o<<=1) ss += __shfl_xor(ss, o);
  __shared__ float red[4];
  if ((t & 63) == 0) red[t>>6] = ss;
  __syncthreads();
  float tot = red[0]+red[1]+red[2]+red[3];
  float rs = rsqrtf(tot * (1.0f/DIM) + 1e-6f);
  float* orow = out + (size_t)blockIdx.x * DIM;
  #pragma unroll
  for (int i=0;i<4;i++) orow[t + 256*i] = v[i]*rs*w[t+256*i];
}

// ---------------- pipelined GEMM, BK=64 (two BK=32 sub-stages), 2 buffers ----------------
// EPI: 1 = outF +=; 4 (NB=2) = outB = bf16(silu(acc0)*acc1);
//      5 = qkv epilogue: isv ? transposed V write [B,NH,HD,S] : RoPE -> outB
template<int EPI, int MT, int NT, int NB>
__device__ __forceinline__ void gemm_pipe(
    const u16* __restrict__ A, const u16* __restrict__ B1, const u16* __restrict__ B2,
    float* __restrict__ outF, u16* __restrict__ outB,
    const float* __restrict__ tab, int isv,
    int N, int K, int m0, int n0)
{
  constexpr int BM = MT*32, BN = NT*32;
  __shared__ __align__(16) u16 As[2][2*BM*32];
  __shared__ __align__(16) u16 Bs[2][2*NB*BN*32];
  const int t = threadIdx.x;
  const int lane = t & 63, wid = t >> 6;
  const int wm = wid >> 1, wn = wid & 1;
  const int l16 = lane & 15, lq = lane >> 4;
  const int srow = lane >> 2, scol = (lane & 3) * 8;
  const size_t rowK16 = (size_t)16 * K;

  const u16* ag  = A  + (size_t)(m0 + wid*(MT*8) + srow) * K + scol;
  const u16* bg1 = B1 + (size_t)(n0 + wid*(NT*8) + srow) * K + scol;
  const u16* bg2 = (NB == 2) ? (B2 + (size_t)(n0 + wid*(NT*8) + srow) * K + scol) : nullptr;

  f32x4 acc[NB][MT][NT];
  #pragma unroll
  for (int j=0;j<NB;j++)
    #pragma unroll
    for (int m=0;m<MT;m++)
      #pragma unroll
      for (int n=0;n<NT;n++) acc[j][m][n] = (f32x4){0.f,0.f,0.f,0.f};

  auto STAGE = [&](int buf, int k0){
    #pragma unroll
    for (int s = 0; s < 2; ++s){
      u16* al = &As[buf][(s*BM + wid*(MT*8))*32];
      #pragma unroll
      for (int pp = 0; pp < MT/2; ++pp)
        gload16(ag + s*32 + pp*rowK16 + k0, al + pp*512);
      u16* bl = &Bs[buf][(s*BN + wid*(NT*8))*32];
      #pragma unroll
      for (int pp = 0; pp < NT/2; ++pp)
        gload16(bg1 + s*32 + pp*rowK16 + k0, bl + pp*512);
      if (NB == 2) {
        u16* b2l = &Bs[buf][((2+s)*BN + wid*(NT*8))*32];
        #pragma unroll
        for (int pp = 0; pp < NT/2; ++pp)
          gload16(bg2 + s*32 + pp*rowK16 + k0, b2l + pp*512);
      }
    }
  };

  const int nt = K >> 6;
  STAGE(0, 0);
  __syncthreads();
  int cur = 0;
  for (int tt = 0; tt < nt; ++tt) {
    if (tt + 1 < nt) STAGE(cur ^ 1, (tt + 1) * 64);
    #pragma unroll
    for (int kk = 0; kk < 2; ++kk){
      short8 af[MT];
      #pragma unroll
      for (int m=0;m<MT;m++) af[m] = *(const short8*)&As[cur][(kk*BM + wm*(MT*16) + m*16 + l16)*32 + lq*8];
      #pragma unroll
      for (int j=0;j<NB;j++){
        short8 bfr[NT];
        #pragma unroll
        for (int n=0;n<NT;n++) bfr[n] = *(const short8*)&Bs[cur][((j*2+kk)*BN + wn*(NT*16) + n*16 + l16)*32 + lq*8];
        #pragma unroll
        for (int m=0;m<MT;m++)
          #pragma unroll
          for (int n=0;n<NT;n++)
            acc[j][m][n] = __builtin_amdgcn_mfma_f32_16x16x32_bf16(af[m], bfr[n], acc[j][m][n], 0, 0, 0);
      }
    }
    if (tt + 1 < nt) { __syncthreads(); cur ^= 1; }
  }

  #pragma unroll
  for (int m=0;m<MT;m++){
    int row = m0 + wm*(MT*16) + m*16 + lq*4;
    #pragma unroll
    for (int n=0;n<NT;n++){
      int col = n0 + wn*(NT*16) + n*16 + l16;
      if (EPI == 1){
        #pragma unroll
        for (int i=0;i<4;i++)
          outF[(size_t)(row+i)*N + col] += acc[0][m][n][i];
      } else if (EPI == 4){
        #pragma unroll
        for (int i=0;i<4;i++){
          float v1 = acc[0][m][n][i];
          float s = v1 / (1.0f + __expf(-v1));
          outB[(size_t)(row+i)*N + col] = f2bf(s * acc[1][m][n][i]);
        }
      } else if (EPI == 5){
        if (isv){
          int bidx = row >> 10, s0 = row & (S_LEN-1);
          int hh = col >> 6, d = col & 63;
          u16x4 pk;
          #pragma unroll
          for (int i=0;i<4;i++) pk[i] = f2bf(acc[0][m][n][i]);
          *(u16x4*)&outB[(((size_t)bidx*NH + hh)*HD + d)*S_LEN + s0] = pk;
        } else {
          int s0 = row & (S_LEN-1);
          int d = col & 63, kk2 = d >> 1;
          float sgn = (d & 1) ? 1.f : -1.f;
          #pragma unroll
          for (int i=0;i<4;i++){
            float val = acc[0][m][n][i];
            float par = __shfl_xor(val, 1);
            float c  = tab[((s0+i)*32 + kk2)*2];
            float sn = tab[((s0+i)*32 + kk2)*2 + 1];
            outB[(size_t)(row+i)*DIM + col] = f2bf(val*c + sgn*par*sn);
          }
        }
      }
    }
  }
}

template<int EPI, int MT, int NT>
__global__ __launch_bounds__(256) void gemm_k(const u16* __restrict__ A,
    const u16* __restrict__ Bt, float* __restrict__ outF,
    u16* __restrict__ outB, int N, int K)
{
  int nwg = gridDim.x * gridDim.y;
  int s = xcdswz(blockIdx.y * gridDim.x + blockIdx.x, nwg);
  int sx = s % gridDim.x, sy = s / gridDim.x;
  gemm_pipe<EPI,MT,NT,1>(A, Bt, nullptr, outF, outB, nullptr, 0, N, K,
                         sy*(MT*32), sx*(NT*32));
}

// fused FFN: g = bf16( silu(xn@w1) * (xn@w3) )  BM=64, BN=128 x2 (MT=2,NT=4)
__global__ __launch_bounds__(256) void gemm_ffn13_k(const u16* __restrict__ A,
    const u16* __restrict__ W1t, const u16* __restrict__ W3t, u16* __restrict__ g)
{
  int nwg = gridDim.x * gridDim.y;
  int s = xcdswz(blockIdx.y * gridDim.x + blockIdx.x, nwg);
  int sx = s % gridDim.x, sy = s / gridDim.x;
  gemm_pipe<4,2,4,2>(A, W1t, W3t, nullptr, g, nullptr, 0, HID, DIM,
                     sy*64, sx*128);
}

// qkv + fused rope (q,k) / transposed write (v). BM=128, BN=64; grid.x = 48.
__global__ __launch_bounds__(256) void gemm_qkv_k(const u16* __restrict__ A,
    const u16* __restrict__ WqT, const u16* __restrict__ WkT, const u16* __restrict__ WvT,
    u16* __restrict__ q, u16* __restrict__ k, u16* __restrict__ vt,
    const float* __restrict__ tab)
{
  int nwg = gridDim.x * gridDim.y;
  int s = xcdswz(blockIdx.y * gridDim.x + blockIdx.x, nwg);
  int sx = s % gridDim.x, sy = s / gridDim.x;
  int which = sx >> 4;
  int n0 = (sx & 15) * 64;
  const u16* Bt = (which==0) ? WqT : (which==1 ? WkT : WvT);
  u16* o = (which==0) ? q : (which==1 ? k : vt);
  gemm_pipe<5,4,2,1>(A, Bt, nullptr, nullptr, o, tab, which==2, DIM, DIM,
                     sy*128, n0);
}

// ---------------- flash attention: swapped-operand + cooperative LDS dbuf, KVBLK=128 ----
// log2-domain online softmax + T13 defer-rescale (skip rescale when pm <= m+8 wave-wide).
__global__ __launch_bounds__(256) void attn_k(const u16* __restrict__ Q,
    const u16* __restrict__ Kt, const u16* __restrict__ Vt,
    u16* __restrict__ O, const int* __restrict__ spp)
{
  __shared__ __align__(16) u16 Kl[2][128*64];
  __shared__ __align__(16) u16 Vl[2][64*128];
  const float NEG_INF = -__builtin_inff();
  int t = threadIdx.x, lane = t & 63, wid = t >> 6;
  int l16 = lane & 15, lq = lane >> 4;
  int nwg = gridDim.x * gridDim.y;
  int sblk = xcdswz(blockIdx.y * gridDim.x + blockIdx.x, nwg);
  int sx = sblk % gridDim.x, sy = sblk / gridDim.x;
  int q0b = sx * 64;
  int q0 = q0b + wid * 16;
  int b = sy >> 4, hh = sy & 15;
  int spos = *spp;
  const float scale2 = 0.125f * 1.44269504f;   // scale * log2(e): exp -> single v_exp_f32
  size_t bh = ((size_t)(b * S_LEN) * NH + hh) * HD;
  const u16* vtb = Vt + (size_t)sy * HD * S_LEN;  // [d][s]
  #define AOFF(s, d) (bh + (size_t)(s) * (NH*HD) + (d))

  short8 qf0 = *(const short8*)(Q + AOFF(q0 + l16, lq*8));
  short8 qf1 = *(const short8*)(Q + AOFF(q0 + l16, 32 + lq*8));

  f32x4 oa[4];
  #pragma unroll
  for (int j=0;j<4;j++) oa[j] = (f32x4){0.f,0.f,0.f,0.f};
  float m = NEG_INF, l = 0.f;                   // m in log2 domain
  int qrow = q0 + l16 + spos;
  int qmax = q0 + 15 + spos;
  int nkb = q0b + 64 + spos; if (nkb > S_LEN) nkb = S_LEN;

  auto STAGE = [&](int buf, int kbs){
    #pragma unroll
    for (int p=0;p<4;p++){
      int kr = wid*32 + p*8 + (lane>>3);
      gload16(Kt + AOFF(kbs + kr, ((lane&7)^(lane>>3))*8), &Kl[buf][(wid*32 + p*8)*64]);
    }
    #pragma unroll
    for (int p=0;p<4;p++){
      int vr = wid*16 + p*4 + (lane>>4);
      gload16(vtb + (size_t)vr*S_LEN + kbs + (((lane&15)^(vr&7))*8), &Vl[buf][(wid*16 + p*4)*128]);
    }
  };

  STAGE(0, 0);
  __syncthreads();
  int cur = 0;
  for (int kb = 0; kb < nkb; kb += 128) {
    if (kb + 128 < nkb) STAGE(cur ^ 1, kb + 128);
    int ktmax = (qmax + 1 - kb + 15) >> 4; if (ktmax > 8) ktmax = 8;

    f32x4 s[8];
    __builtin_amdgcn_s_setprio(1);
    #pragma unroll
    for (int kt=0; kt<8; ++kt) if (kt < ktmax) {
      const u16* kr = &Kl[cur][(kt*16 + l16)*64];
      short8 kf0 = *(const short8*)(kr + (( lq      ^ (l16&7)) * 8));
      short8 kf1 = *(const short8*)(kr + (((4 + lq) ^ (l16&7)) * 8));
      f32x4 z = (f32x4){0.f,0.f,0.f,0.f};
      z = __builtin_amdgcn_mfma_f32_16x16x32_bf16(kf0, qf0, z, 0,0,0);
      z = __builtin_amdgcn_mfma_f32_16x16x32_bf16(kf1, qf1, z, 0,0,0);
      s[kt] = z;
    }
    __builtin_amdgcn_s_setprio(0);

    float p[32];
    #pragma unroll
    for (int kt=0; kt<8; ++kt)
      #pragma unroll
      for (int i=0;i<4;i++){
        int krow = kb + kt*16 + lq*4 + i;
        p[kt*4+i] = (kt < ktmax && krow <= qrow) ? s[kt][i]*scale2 : NEG_INF;
      }
    float pm = p[0];
    #pragma unroll
    for (int x=1;x<32;x++) pm = fmaxf(pm, p[x]);
    pm = fmaxf(pm, __shfl_xor(pm, 16));
    pm = fmaxf(pm, __shfl_xor(pm, 32));
    // T13 defer-rescale: only rescale when some q's max grew by > 8 (log2 units)
    if (!__all(pm <= m + 8.0f)) {
      float mn = fmaxf(m, pm);
      float corr = exp2f(m - mn);
      m = mn;
      l *= corr;
      #pragma unroll
      for (int j=0;j<4;j++) oa[j] *= corr;
    }
    float rs = 0.f;
    #pragma unroll
    for (int x=0;x<32;x++){ p[x] = exp2f(p[x] - m); rs += p[x]; }
    rs += __shfl_xor(rs, 16);
    rs += __shfl_xor(rs, 32);
    l += rs;

    __builtin_amdgcn_s_setprio(1);
    #pragma unroll
    for (int kt=0; kt<8; ++kt) if (kt < ktmax) {
      short4v pb;
      #pragma unroll
      for (int i=0;i<4;i++) pb[i] = (short)f2bf(p[kt*4+i]);
      #pragma unroll
      for (int j=0;j<4;j++){
        int rv = j*16 + l16;
        int ck = (kt*2 + (lq>>1)) ^ (l16&7);
        short4v va = *(const short4v*)(&Vl[cur][rv*128 + ck*8 + (lq&1)*4]);
        oa[j] = MFMA_PV(va, pb, oa[j]);
      }
    }
    __builtin_amdgcn_s_setprio(0);

    __syncthreads();
    cur ^= 1;
  }

  float inv = 1.0f / l;
  #pragma unroll
  for (int j=0;j<4;j++){
    u16x4 pk;
    #pragma unroll
    for (int i=0;i<4;i++) pk[i] = f2bf(oa[j][i] * inv);
    *(u16x4*)&O[AOFF(q0 + l16, j*16 + lq*4)] = pk;
  }
  #undef AOFF
}

// ---------------- final projection: [2,1024] @ [1024,32000] ----------------
__global__ __launch_bounds__(256) void outproj_k(const float* __restrict__ xf,
    const float* __restrict__ W, float* __restrict__ out)
{
  __shared__ float xs0[512], xs1[512];
  int t = threadIdx.x;
  int kbase = blockIdx.y * 512;
  for (int i = t; i < 512; i += 256){ xs0[i] = xf[kbase + i]; xs1[i] = xf[DIM + kbase + i]; }
  __syncthreads();
  int n = blockIdx.x * 256 + t;
  float a0 = 0.f, a1 = 0.f;
  #pragma unroll 8
  for (int k2 = 0; k2 < 512; ++k2){
    float w = W[(size_t)(kbase + k2) * NVOCAB + n];
    a0 += xs0[k2]*w; a1 += xs1[k2]*w;
  }
  atomicAdd(&out[n], a0);
  atomicAdd(&out[NVOCAB + n], a1);
}

extern "C" void kernel_launch(void* const* d_in, const int* in_sizes, int n_in,
                              void* d_out, int out_size, void* d_ws, size_t ws_size,
                              hipStream_t stream)
{
  const int*   tokens = (const int*)d_in[0];
  const int*   spp    = (const int*)d_in[1];
  const float* temb   = (const float*)d_in[2];
  const float* wq     = (const float*)d_in[3];
  const float* wk     = (const float*)d_in[4];
  const float* wv     = (const float*)d_in[5];
  const float* wo     = (const float*)d_in[6];
  const float* w1     = (const float*)d_in[7];
  const float* w2     = (const float*)d_in[8];
  const float* w3     = (const float*)d_in[9];
  const float* anw    = (const float*)d_in[10];
  const float* fnw    = (const float*)d_in[11];
  const float* finw   = (const float*)d_in[12];
  const float* outw   = (const float*)d_in[13];

  char* p = (char*)d_ws;
  auto carve = [&](size_t nbytes){ char* r = p; p += (nbytes + 255) & ~(size_t)255; return r; };
  const int R = B_SZ * S_LEN;  // 2048 rows
  float* h    = (float*)carve((size_t)R*DIM*4);
  u16* xn     = (u16*)carve((size_t)R*DIM*2);
  u16* qb     = (u16*)carve((size_t)R*DIM*2);
  u16* kb     = (u16*)carve((size_t)R*DIM*2);
  u16* vt     = (u16*)carve((size_t)R*DIM*2);
  u16* ob     = (u16*)carve((size_t)R*DIM*2);
  u16* g      = (u16*)carve((size_t)R*HID*2);
  float* tab  = (float*)carve((size_t)S_LEN*32*2*4);
  float* xfin = (float*)carve((size_t)B_SZ*DIM*4);
  // transposed bf16 weights
  u16* wqT = (u16*)carve((size_t)4*DIM*DIM*2);
  u16* wkT = (u16*)carve((size_t)4*DIM*DIM*2);
  u16* wvT = (u16*)carve((size_t)4*DIM*DIM*2);
  u16* woT = (u16*)carve((size_t)4*DIM*DIM*2);
  u16* w1T = (u16*)carve((size_t)4*DIM*HID*2);
  u16* w3T = (u16*)carve((size_t)4*DIM*HID*2);
  u16* w2T = (u16*)carve((size_t)4*HID*DIM*2);
  (void)ws_size; (void)in_sizes; (void)n_in;

  transpose4_k<<<dim3(16,16,16), 256, 0, stream>>>(wq, wk, wv, wo, wqT, wkT, wvT, woT);
  transpose2_k<<<dim3(44,16,8),  256, 0, stream>>>(w1, w3, w1T, w3T);
  transpose1_k<<<dim3(16,44,4),  256, 0, stream>>>(w2, w2T);

  freqs_k<<<(S_LEN*32)/256, 256, 0, stream>>>(tab, spp);
  embed_k<<<R, 256, 0, stream>>>(tokens, temb, h);

  for (int l = 0; l < 4; ++l) {
    size_t sqo = (size_t)l * DIM * DIM;
    size_t sff = (size_t)l * DIM * HID;
    rmsnorm_k<<<R, 256, 0, stream>>>(h, anw + l*DIM, xn);
    gemm_qkv_k<<<dim3(48, R/128), 256, 0, stream>>>(xn, wqT + sqo, wkT + sqo, wvT + sqo,
                                                    qb, kb, vt, tab);
    attn_k<<<dim3(S_LEN/64, B_SZ*NH), 256, 0, stream>>>(qb, kb, vt, ob, spp);
    gemm_k<1,2,2><<<dim3(DIM/64, R/64), 256, 0, stream>>>(ob, woT + sqo, h, nullptr, DIM, DIM);
    rmsnorm_k<<<R, 256, 0, stream>>>(h, fnw + l*DIM, xn);
    gemm_ffn13_k<<<dim3(HID/128, R/64), 256, 0, stream>>>(xn, w1T + sff, w3T + sff, g);
    gemm_k<1,2,2><<<dim3(DIM/64, R/64), 256, 0, stream>>>(g, w2T + sff, h, nullptr, DIM, HID);
  }
  rmsnorm_last_k<<<B_SZ, 256, 0, stream>>>(h, finw, xfin);
  hipMemsetAsync(d_out, 0, (size_t)out_size * sizeof(float), stream);
  outproj_k<<<dim3(NVOCAB/256, 2), 256, 0, stream>>>(xfin, outw, (float*)d_out);
}

// Round 12
// 724.034 us; speedup vs baseline: 1.1081x; 1.1081x over previous
//
#include <hip/hip_runtime.h>
#include <cstddef>

#define B_SZ 2
#define S_LEN 1024
#define NH 16
#define HD 64
#define DIM 1024
#define HID 2816
#define NVOCAB 32000

typedef __attribute__((ext_vector_type(8))) short short8;
typedef __attribute__((ext_vector_type(4))) short short4v;
typedef __attribute__((ext_vector_type(4))) float f32x4;
typedef __attribute__((ext_vector_type(4))) unsigned short u16x4;
typedef unsigned short u16;

#if __has_builtin(__builtin_amdgcn_mfma_f32_16x16x16_bf16)
#define MFMA_PV(a,b,c) __builtin_amdgcn_mfma_f32_16x16x16_bf16(a,b,c,0,0,0)
#else
#define MFMA_PV(a,b,c) __builtin_amdgcn_mfma_f32_16x16x16bf16_1k(a,b,c,0,0,0)
#endif

static __device__ __forceinline__ u16 f2bf(float f){
  unsigned u = __float_as_uint(f);
  u += 0x7FFFu + ((u >> 16) & 1u);   // RNE
  return (u16)(u >> 16);
}
static __device__ __forceinline__ float bf2f(unsigned u){
  return __uint_as_float(u << 16);
}

// XCD-aware bijective block remap (T1). Requires nwg % 8 == 0 (all our grids comply).
static __device__ __forceinline__ int xcdswz(int bid, int nwg){
  return (bid & 7) * (nwg >> 3) + (bid >> 3);
}

// async global->LDS, 16B per lane. LDS dest = wave-uniform base + lane*16 (linear).
static __device__ __forceinline__ void gload16(const void* g, void* l){
  __builtin_amdgcn_global_load_lds(
    (const __attribute__((address_space(1))) unsigned int*)g,
    (__attribute__((address_space(3))) unsigned int*)l, 16, 0, 0);
}

// ---------------- weight convert + transpose: f32 [K][N] -> bf16 [N][K] ----------------
static __device__ __forceinline__ void tr_body(u16 (*ld)[65],
    const float* __restrict__ in, u16* __restrict__ out, int K, int N)
{
  const int t = threadIdx.x;
  const int n0 = blockIdx.x * 64, k0 = blockIdx.y * 64;
  #pragma unroll
  for (int i = 0; i < 4; ++i){
    int idx = i*256 + t;
    int r = idx >> 4, c4 = (idx & 15) * 4;
    f32x4 v = *(const f32x4*)&in[(size_t)(k0 + r) * N + n0 + c4];
    ld[r][c4+0] = f2bf(v[0]); ld[r][c4+1] = f2bf(v[1]);
    ld[r][c4+2] = f2bf(v[2]); ld[r][c4+3] = f2bf(v[3]);
  }
  __syncthreads();
  #pragma unroll
  for (int i = 0; i < 4; ++i){
    int idx = i*256 + t;
    int c = idx >> 4, r4 = (idx & 15) * 4;
    u16x4 pk;
    pk[0]=ld[r4+0][c]; pk[1]=ld[r4+1][c]; pk[2]=ld[r4+2][c]; pk[3]=ld[r4+3][c];
    *(u16x4*)&out[(size_t)(n0 + c) * K + k0 + r4] = pk;
  }
}

__global__ __launch_bounds__(256) void transpose4_k(
    const float* __restrict__ i0, const float* __restrict__ i1,
    const float* __restrict__ i2, const float* __restrict__ i3,
    u16* __restrict__ o0, u16* __restrict__ o1, u16* __restrict__ o2, u16* __restrict__ o3)
{
  __shared__ u16 ld[64][65];
  int w = blockIdx.z >> 2, lyr = blockIdx.z & 3;
  const float* in = (w==0)?i0:(w==1)?i1:(w==2)?i2:i3;
  u16*      out = (w==0)?o0:(w==1)?o1:(w==2)?o2:o3;
  tr_body(ld, in + (size_t)lyr*DIM*DIM, out + (size_t)lyr*DIM*DIM, DIM, DIM);
}

__global__ __launch_bounds__(256) void transpose2_k(
    const float* __restrict__ i0, const float* __restrict__ i1,
    u16* __restrict__ o0, u16* __restrict__ o1)
{
  __shared__ u16 ld[64][65];
  int w = blockIdx.z >> 2, lyr = blockIdx.z & 3;
  const float* in = w ? i1 : i0;
  u16*      out = w ? o1 : o0;
  tr_body(ld, in + (size_t)lyr*DIM*HID, out + (size_t)lyr*DIM*HID, DIM, HID);
}

__global__ __launch_bounds__(256) void transpose1_k(
    const float* __restrict__ in, u16* __restrict__ out)
{
  __shared__ u16 ld[64][65];
  tr_body(ld, in + (size_t)blockIdx.z*HID*DIM, out + (size_t)blockIdx.z*HID*DIM, HID, DIM);
}

// ---------------- embedding gather ----------------
__global__ __launch_bounds__(256) void embed_k(const int* __restrict__ tok,
    const float* __restrict__ emb, float* __restrict__ h)
{
  int row = blockIdx.x;
  int t = tok[row];
  const f32x4* src = (const f32x4*)(emb + (size_t)t * DIM);
  f32x4* dst = (f32x4*)(h + (size_t)row * DIM);
  dst[threadIdx.x] = src[threadIdx.x];
}

// ---------------- RoPE cos/sin table ----------------
__global__ __launch_bounds__(256) void freqs_k(float* __restrict__ tab,
    const int* __restrict__ spp)
{
  int i = blockIdx.x * 256 + threadIdx.x;   // [0, S_LEN*32)
  int s = i >> 5, kk = i & 31;
  float inv = powf(10000.0f, -(float)kk * (1.0f/32.0f));
  float ang = (float)(*spp + s) * inv;
  tab[i*2]   = cosf(ang);
  tab[i*2+1] = sinf(ang);
}

// ---------------- RMSNorm -> bf16 ----------------
__global__ __launch_bounds__(256) void rmsnorm_k(const float* __restrict__ x,
    const float* __restrict__ w, u16* __restrict__ out)
{
  int row = blockIdx.x, t = threadIdx.x;
  const float* xr = x + (size_t)row * DIM;
  float v[4]; float ss = 0.f;
  #pragma unroll
  for (int i=0;i<4;i++){ v[i] = xr[t + 256*i]; ss += v[i]*v[i]; }
  #pragma unroll
  for (int o=1;o<64;o<<=1) ss += __shfl_xor(ss, o);
  __shared__ float red[4];
  if ((t & 63) == 0) red[t>>6] = ss;
  __syncthreads();
  float tot = red[0]+red[1]+red[2]+red[3];
  float rs = rsqrtf(tot * (1.0f/DIM) + 1e-6f);
  u16* orow = out + (size_t)row * DIM;
  #pragma unroll
  for (int i=0;i<4;i++) orow[t + 256*i] = f2bf(v[i]*rs*w[t+256*i]);
}

// RMSNorm of last-position rows -> f32
__global__ __launch_bounds__(256) void rmsnorm_last_k(const float* __restrict__ x,
    const float* __restrict__ w, float* __restrict__ out)
{
  int row = (blockIdx.x + 1) * S_LEN - 1;
  int t = threadIdx.x;
  const float* xr = x + (size_t)row * DIM;
  float v[4]; float ss = 0.f;
  #pragma unroll
  for (int i=0;i<4;i++){ v[i] = xr[t + 256*i]; ss += v[i]*v[i]; }
  #pragma unroll
  for (int o=1;o<64;o<<=1) ss += __shfl_xor(ss, o);
  __shared__ float red[4];
  if ((t & 63) == 0) red[t>>6] = ss;
  __syncthreads();
  float tot = red[0]+red[1]+red[2]+red[3];
  float rs = rsqrtf(tot * (1.0f/DIM) + 1e-6f);
  float* orow = out + (size_t)blockIdx.x * DIM;
  #pragma unroll
  for (int i=0;i<4;i++) orow[t + 256*i] = v[i]*rs*w[t+256*i];
}

// ---------------- pipelined GEMM, BK=64 (two BK=32 sub-stages), 2 buffers ----------------
// EPI: 1 = outF +=; 4 (NB=2) = outB = bf16(silu(acc0)*acc1);
//      5 = qkv epilogue: isv ? transposed V write [B,NH,HD,S] : RoPE -> outB
template<int EPI, int MT, int NT, int NB>
__device__ __forceinline__ void gemm_pipe(
    const u16* __restrict__ A, const u16* __restrict__ B1, const u16* __restrict__ B2,
    float* __restrict__ outF, u16* __restrict__ outB,
    const float* __restrict__ tab, int isv,
    int N, int K, int m0, int n0)
{
  constexpr int BM = MT*32, BN = NT*32;
  __shared__ __align__(16) u16 As[2][2*BM*32];
  __shared__ __align__(16) u16 Bs[2][2*NB*BN*32];
  const int t = threadIdx.x;
  const int lane = t & 63, wid = t >> 6;
  const int wm = wid >> 1, wn = wid & 1;
  const int l16 = lane & 15, lq = lane >> 4;
  const int srow = lane >> 2, scol = (lane & 3) * 8;
  const size_t rowK16 = (size_t)16 * K;

  const u16* ag  = A  + (size_t)(m0 + wid*(MT*8) + srow) * K + scol;
  const u16* bg1 = B1 + (size_t)(n0 + wid*(NT*8) + srow) * K + scol;
  const u16* bg2 = (NB == 2) ? (B2 + (size_t)(n0 + wid*(NT*8) + srow) * K + scol) : nullptr;

  f32x4 acc[NB][MT][NT];
  #pragma unroll
  for (int j=0;j<NB;j++)
    #pragma unroll
    for (int m=0;m<MT;m++)
      #pragma unroll
      for (int n=0;n<NT;n++) acc[j][m][n] = (f32x4){0.f,0.f,0.f,0.f};

  auto STAGE = [&](int buf, int k0){
    #pragma unroll
    for (int s = 0; s < 2; ++s){
      u16* al = &As[buf][(s*BM + wid*(MT*8))*32];
      #pragma unroll
      for (int pp = 0; pp < MT/2; ++pp)
        gload16(ag + s*32 + pp*rowK16 + k0, al + pp*512);
      u16* bl = &Bs[buf][(s*BN + wid*(NT*8))*32];
      #pragma unroll
      for (int pp = 0; pp < NT/2; ++pp)
        gload16(bg1 + s*32 + pp*rowK16 + k0, bl + pp*512);
      if (NB == 2) {
        u16* b2l = &Bs[buf][((2+s)*BN + wid*(NT*8))*32];
        #pragma unroll
        for (int pp = 0; pp < NT/2; ++pp)
          gload16(bg2 + s*32 + pp*rowK16 + k0, b2l + pp*512);
      }
    }
  };

  const int nt = K >> 6;
  STAGE(0, 0);
  __syncthreads();
  int cur = 0;
  for (int tt = 0; tt < nt; ++tt) {
    if (tt + 1 < nt) STAGE(cur ^ 1, (tt + 1) * 64);
    #pragma unroll
    for (int kk = 0; kk < 2; ++kk){
      short8 af[MT];
      #pragma unroll
      for (int m=0;m<MT;m++) af[m] = *(const short8*)&As[cur][(kk*BM + wm*(MT*16) + m*16 + l16)*32 + lq*8];
      #pragma unroll
      for (int j=0;j<NB;j++){
        short8 bfr[NT];
        #pragma unroll
        for (int n=0;n<NT;n++) bfr[n] = *(const short8*)&Bs[cur][((j*2+kk)*BN + wn*(NT*16) + n*16 + l16)*32 + lq*8];
        #pragma unroll
        for (int m=0;m<MT;m++)
          #pragma unroll
          for (int n=0;n<NT;n++)
            acc[j][m][n] = __builtin_amdgcn_mfma_f32_16x16x32_bf16(af[m], bfr[n], acc[j][m][n], 0, 0, 0);
      }
    }
    if (tt + 1 < nt) { __syncthreads(); cur ^= 1; }
  }

  #pragma unroll
  for (int m=0;m<MT;m++){
    int row = m0 + wm*(MT*16) + m*16 + lq*4;
    #pragma unroll
    for (int n=0;n<NT;n++){
      int col = n0 + wn*(NT*16) + n*16 + l16;
      if (EPI == 1){
        #pragma unroll
        for (int i=0;i<4;i++)
          outF[(size_t)(row+i)*N + col] += acc[0][m][n][i];
      } else if (EPI == 4){
        #pragma unroll
        for (int i=0;i<4;i++){
          float v1 = acc[0][m][n][i];
          float s = v1 / (1.0f + __expf(-v1));
          outB[(size_t)(row+i)*N + col] = f2bf(s * acc[1][m][n][i]);
        }
      } else if (EPI == 5){
        if (isv){
          int bidx = row >> 10, s0 = row & (S_LEN-1);
          int hh = col >> 6, d = col & 63;
          u16x4 pk;
          #pragma unroll
          for (int i=0;i<4;i++) pk[i] = f2bf(acc[0][m][n][i]);
          *(u16x4*)&outB[(((size_t)bidx*NH + hh)*HD + d)*S_LEN + s0] = pk;
        } else {
          int s0 = row & (S_LEN-1);
          int d = col & 63, kk2 = d >> 1;
          float sgn = (d & 1) ? 1.f : -1.f;
          #pragma unroll
          for (int i=0;i<4;i++){
            float val = acc[0][m][n][i];
            float par = __shfl_xor(val, 1);
            float c  = tab[((s0+i)*32 + kk2)*2];
            float sn = tab[((s0+i)*32 + kk2)*2 + 1];
            outB[(size_t)(row+i)*DIM + col] = f2bf(val*c + sgn*par*sn);
          }
        }
      }
    }
  }
}

template<int EPI, int MT, int NT>
__global__ __launch_bounds__(256) void gemm_k(const u16* __restrict__ A,
    const u16* __restrict__ Bt, float* __restrict__ outF,
    u16* __restrict__ outB, int N, int K)
{
  int nwg = gridDim.x * gridDim.y;
  int s = xcdswz(blockIdx.y * gridDim.x + blockIdx.x, nwg);
  int sx = s % gridDim.x, sy = s / gridDim.x;
  gemm_pipe<EPI,MT,NT,1>(A, Bt, nullptr, outF, outB, nullptr, 0, N, K,
                         sy*(MT*32), sx*(NT*32));
}

// fused FFN: g = bf16( silu(xn@w1) * (xn@w3) )  BM=64, BN=64 x2 (round-10 proven tile)
__global__ __launch_bounds__(256) void gemm_ffn13_k(const u16* __restrict__ A,
    const u16* __restrict__ W1t, const u16* __restrict__ W3t, u16* __restrict__ g)
{
  int nwg = gridDim.x * gridDim.y;
  int s = xcdswz(blockIdx.y * gridDim.x + blockIdx.x, nwg);
  int sx = s % gridDim.x, sy = s / gridDim.x;
  gemm_pipe<4,2,2,2>(A, W1t, W3t, nullptr, g, nullptr, 0, HID, DIM,
                     sy*64, sx*64);
}

// qkv + fused rope (q,k) / transposed write (v). BM=128, BN=64; grid.x = 48.
__global__ __launch_bounds__(256) void gemm_qkv_k(const u16* __restrict__ A,
    const u16* __restrict__ WqT, const u16* __restrict__ WkT, const u16* __restrict__ WvT,
    u16* __restrict__ q, u16* __restrict__ k, u16* __restrict__ vt,
    const float* __restrict__ tab)
{
  int nwg = gridDim.x * gridDim.y;
  int s = xcdswz(blockIdx.y * gridDim.x + blockIdx.x, nwg);
  int sx = s % gridDim.x, sy = s / gridDim.x;
  int which = sx >> 4;
  int n0 = (sx & 15) * 64;
  const u16* Bt = (which==0) ? WqT : (which==1 ? WkT : WvT);
  u16* o = (which==0) ? q : (which==1 ? k : vt);
  gemm_pipe<5,4,2,1>(A, Bt, nullptr, nullptr, o, tab, which==2, DIM, DIM,
                     sy*128, n0);
}

// ---------------- flash attention: swapped-operand + cooperative LDS dbuf, KVBLK=128 ----
// log2-domain online softmax + T13 defer-rescale (skip rescale when pm <= m+8 wave-wide).
__global__ __launch_bounds__(256) void attn_k(const u16* __restrict__ Q,
    const u16* __restrict__ Kt, const u16* __restrict__ Vt,
    u16* __restrict__ O, const int* __restrict__ spp)
{
  __shared__ __align__(16) u16 Kl[2][128*64];
  __shared__ __align__(16) u16 Vl[2][64*128];
  const float NEG_INF = -__builtin_inff();
  int t = threadIdx.x, lane = t & 63, wid = t >> 6;
  int l16 = lane & 15, lq = lane >> 4;
  int nwg = gridDim.x * gridDim.y;
  int sblk = xcdswz(blockIdx.y * gridDim.x + blockIdx.x, nwg);
  int sx = sblk % gridDim.x, sy = sblk / gridDim.x;
  int q0b = sx * 64;
  int q0 = q0b + wid * 16;
  int b = sy >> 4, hh = sy & 15;
  int spos = *spp;
  const float scale2 = 0.125f * 1.44269504f;   // scale * log2(e): exp -> single v_exp_f32
  size_t bh = ((size_t)(b * S_LEN) * NH + hh) * HD;
  const u16* vtb = Vt + (size_t)sy * HD * S_LEN;  // [d][s]
  #define AOFF(s, d) (bh + (size_t)(s) * (NH*HD) + (d))

  short8 qf0 = *(const short8*)(Q + AOFF(q0 + l16, lq*8));
  short8 qf1 = *(const short8*)(Q + AOFF(q0 + l16, 32 + lq*8));

  f32x4 oa[4];
  #pragma unroll
  for (int j=0;j<4;j++) oa[j] = (f32x4){0.f,0.f,0.f,0.f};
  float m = NEG_INF, l = 0.f;                   // m in log2 domain
  int qrow = q0 + l16 + spos;
  int qmax = q0 + 15 + spos;
  int nkb = q0b + 64 + spos; if (nkb > S_LEN) nkb = S_LEN;

  auto STAGE = [&](int buf, int kbs){
    #pragma unroll
    for (int p=0;p<4;p++){
      int kr = wid*32 + p*8 + (lane>>3);
      gload16(Kt + AOFF(kbs + kr, ((lane&7)^(lane>>3))*8), &Kl[buf][(wid*32 + p*8)*64]);
    }
    #pragma unroll
    for (int p=0;p<4;p++){
      int vr = wid*16 + p*4 + (lane>>4);
      gload16(vtb + (size_t)vr*S_LEN + kbs + (((lane&15)^(vr&7))*8), &Vl[buf][(wid*16 + p*4)*128]);
    }
  };

  STAGE(0, 0);
  __syncthreads();
  int cur = 0;
  for (int kb = 0; kb < nkb; kb += 128) {
    if (kb + 128 < nkb) STAGE(cur ^ 1, kb + 128);
    int ktmax = (qmax + 1 - kb + 15) >> 4; if (ktmax > 8) ktmax = 8;

    f32x4 s[8];
    __builtin_amdgcn_s_setprio(1);
    #pragma unroll
    for (int kt=0; kt<8; ++kt) if (kt < ktmax) {
      const u16* kr = &Kl[cur][(kt*16 + l16)*64];
      short8 kf0 = *(const short8*)(kr + (( lq      ^ (l16&7)) * 8));
      short8 kf1 = *(const short8*)(kr + (((4 + lq) ^ (l16&7)) * 8));
      f32x4 z = (f32x4){0.f,0.f,0.f,0.f};
      z = __builtin_amdgcn_mfma_f32_16x16x32_bf16(kf0, qf0, z, 0,0,0);
      z = __builtin_amdgcn_mfma_f32_16x16x32_bf16(kf1, qf1, z, 0,0,0);
      s[kt] = z;
    }
    __builtin_amdgcn_s_setprio(0);

    float p[32];
    #pragma unroll
    for (int kt=0; kt<8; ++kt)
      #pragma unroll
      for (int i=0;i<4;i++){
        int krow = kb + kt*16 + lq*4 + i;
        p[kt*4+i] = (kt < ktmax && krow <= qrow) ? s[kt][i]*scale2 : NEG_INF;
      }
    float pm = p[0];
    #pragma unroll
    for (int x=1;x<32;x++) pm = fmaxf(pm, p[x]);
    pm = fmaxf(pm, __shfl_xor(pm, 16));
    pm = fmaxf(pm, __shfl_xor(pm, 32));
    // T13 defer-rescale: only rescale when some q's max grew by > 8 (log2 units)
    if (!__all(pm <= m + 8.0f)) {
      float mn = fmaxf(m, pm);
      float corr = exp2f(m - mn);
      m = mn;
      l *= corr;
      #pragma unroll
      for (int j=0;j<4;j++) oa[j] *= corr;
    }
    float rs = 0.f;
    #pragma unroll
    for (int x=0;x<32;x++){ p[x] = exp2f(p[x] - m); rs += p[x]; }
    rs += __shfl_xor(rs, 16);
    rs += __shfl_xor(rs, 32);
    l += rs;

    __builtin_amdgcn_s_setprio(1);
    #pragma unroll
    for (int kt=0; kt<8; ++kt) if (kt < ktmax) {
      short4v pb;
      #pragma unroll
      for (int i=0;i<4;i++) pb[i] = (short)f2bf(p[kt*4+i]);
      #pragma unroll
      for (int j=0;j<4;j++){
        int rv = j*16 + l16;
        int ck = (kt*2 + (lq>>1)) ^ (l16&7);
        short4v va = *(const short4v*)(&Vl[cur][rv*128 + ck*8 + (lq&1)*4]);
        oa[j] = MFMA_PV(va, pb, oa[j]);
      }
    }
    __builtin_amdgcn_s_setprio(0);

    __syncthreads();
    cur ^= 1;
  }

  float inv = 1.0f / l;
  #pragma unroll
  for (int j=0;j<4;j++){
    u16x4 pk;
    #pragma unroll
    for (int i=0;i<4;i++) pk[i] = f2bf(oa[j][i] * inv);
    *(u16x4*)&O[AOFF(q0 + l16, j*16 + lq*4)] = pk;
  }
  #undef AOFF
}

// ---------------- final projection: [2,1024] @ [1024,32000] ----------------
__global__ __launch_bounds__(256) void outproj_k(const float* __restrict__ xf,
    const float* __restrict__ W, float* __restrict__ out)
{
  __shared__ float xs0[512], xs1[512];
  int t = threadIdx.x;
  int kbase = blockIdx.y * 512;
  for (int i = t; i < 512; i += 256){ xs0[i] = xf[kbase + i]; xs1[i] = xf[DIM + kbase + i]; }
  __syncthreads();
  int n = blockIdx.x * 256 + t;
  float a0 = 0.f, a1 = 0.f;
  #pragma unroll 8
  for (int k2 = 0; k2 < 512; ++k2){
    float w = W[(size_t)(kbase + k2) * NVOCAB + n];
    a0 += xs0[k2]*w; a1 += xs1[k2]*w;
  }
  atomicAdd(&out[n], a0);
  atomicAdd(&out[NVOCAB + n], a1);
}

extern "C" void kernel_launch(void* const* d_in, const int* in_sizes, int n_in,
                              void* d_out, int out_size, void* d_ws, size_t ws_size,
                              hipStream_t stream)
{
  const int*   tokens = (const int*)d_in[0];
  const int*   spp    = (const int*)d_in[1];
  const float* temb   = (const float*)d_in[2];
  const float* wq     = (const float*)d_in[3];
  const float* wk     = (const float*)d_in[4];
  const float* wv     = (const float*)d_in[5];
  const float* wo     = (const float*)d_in[6];
  const float* w1     = (const float*)d_in[7];
  const float* w2     = (const float*)d_in[8];
  const float* w3     = (const float*)d_in[9];
  const float* anw    = (const float*)d_in[10];
  const float* fnw    = (const float*)d_in[11];
  const float* finw   = (const float*)d_in[12];
  const float* outw   = (const float*)d_in[13];

  char* p = (char*)d_ws;
  auto carve = [&](size_t nbytes){ char* r = p; p += (nbytes + 255) & ~(size_t)255; return r; };
  const int R = B_SZ * S_LEN;  // 2048 rows
  float* h    = (float*)carve((size_t)R*DIM*4);
  u16* xn     = (u16*)carve((size_t)R*DIM*2);
  u16* qb     = (u16*)carve((size_t)R*DIM*2);
  u16* kb     = (u16*)carve((size_t)R*DIM*2);
  u16* vt     = (u16*)carve((size_t)R*DIM*2);
  u16* ob     = (u16*)carve((size_t)R*DIM*2);
  u16* g      = (u16*)carve((size_t)R*HID*2);
  float* tab  = (float*)carve((size_t)S_LEN*32*2*4);
  float* xfin = (float*)carve((size_t)B_SZ*DIM*4);
  // transposed bf16 weights
  u16* wqT = (u16*)carve((size_t)4*DIM*DIM*2);
  u16* wkT = (u16*)carve((size_t)4*DIM*DIM*2);
  u16* wvT = (u16*)carve((size_t)4*DIM*DIM*2);
  u16* woT = (u16*)carve((size_t)4*DIM*DIM*2);
  u16* w1T = (u16*)carve((size_t)4*DIM*HID*2);
  u16* w3T = (u16*)carve((size_t)4*DIM*HID*2);
  u16* w2T = (u16*)carve((size_t)4*HID*DIM*2);
  (void)ws_size; (void)in_sizes; (void)n_in;

  transpose4_k<<<dim3(16,16,16), 256, 0, stream>>>(wq, wk, wv, wo, wqT, wkT, wvT, woT);
  transpose2_k<<<dim3(44,16,8),  256, 0, stream>>>(w1, w3, w1T, w3T);
  transpose1_k<<<dim3(16,44,4),  256, 0, stream>>>(w2, w2T);

  freqs_k<<<(S_LEN*32)/256, 256, 0, stream>>>(tab, spp);
  embed_k<<<R, 256, 0, stream>>>(tokens, temb, h);

  for (int l = 0; l < 4; ++l) {
    size_t sqo = (size_t)l * DIM * DIM;
    size_t sff = (size_t)l * DIM * HID;
    rmsnorm_k<<<R, 256, 0, stream>>>(h, anw + l*DIM, xn);
    gemm_qkv_k<<<dim3(48, R/128), 256, 0, stream>>>(xn, wqT + sqo, wkT + sqo, wvT + sqo,
                                                    qb, kb, vt, tab);
    attn_k<<<dim3(S_LEN/64, B_SZ*NH), 256, 0, stream>>>(qb, kb, vt, ob, spp);
    gemm_k<1,2,2><<<dim3(DIM/64, R/64), 256, 0, stream>>>(ob, woT + sqo, h, nullptr, DIM, DIM);
    rmsnorm_k<<<R, 256, 0, stream>>>(h, fnw + l*DIM, xn);
    gemm_ffn13_k<<<dim3(HID/64, R/64), 256, 0, stream>>>(xn, w1T + sff, w3T + sff, g);
    gemm_k<1,2,2><<<dim3(DIM/64, R/64), 256, 0, stream>>>(g, w2T + sff, h, nullptr, DIM, HID);
  }
  rmsnorm_last_k<<<B_SZ, 256, 0, stream>>>(h, finw, xfin);
  hipMemsetAsync(d_out, 0, (size_t)out_size * sizeof(float), stream);
  outproj_k<<<dim3(NVOCAB/256, 2), 256, 0, stream>>>(xfin, outw, (float*)d_out);
}

// Round 13
// 715.016 us; speedup vs baseline: 1.1220x; 1.0126x over previous
//
#include <hip/hip_runtime.h>
#include <cstddef>

#define B_SZ 2
#define S_LEN 1024
#define NH 16
#define HD 64
#define DIM 1024
#define HID 2816
#define NVOCAB 32000

typedef __attribute__((ext_vector_type(8))) short short8;
typedef __attribute__((ext_vector_type(4))) short short4v;
typedef __attribute__((ext_vector_type(4))) float f32x4;
typedef __attribute__((ext_vector_type(4))) unsigned short u16x4;
typedef unsigned short u16;

#if __has_builtin(__builtin_amdgcn_mfma_f32_16x16x16_bf16)
#define MFMA_PV(a,b,c) __builtin_amdgcn_mfma_f32_16x16x16_bf16(a,b,c,0,0,0)
#else
#define MFMA_PV(a,b,c) __builtin_amdgcn_mfma_f32_16x16x16bf16_1k(a,b,c,0,0,0)
#endif

static __device__ __forceinline__ u16 f2bf(float f){
  unsigned u = __float_as_uint(f);
  u += 0x7FFFu + ((u >> 16) & 1u);   // RNE
  return (u16)(u >> 16);
}
static __device__ __forceinline__ float bf2f(unsigned u){
  return __uint_as_float(u << 16);
}

// XCD-aware bijective block remap (T1). Requires nwg % 8 == 0 (all our grids comply).
static __device__ __forceinline__ int xcdswz(int bid, int nwg){
  return (bid & 7) * (nwg >> 3) + (bid >> 3);
}

// async global->LDS, 16B per lane. LDS dest = wave-uniform base + lane*16 (linear).
static __device__ __forceinline__ void gload16(const void* g, void* l){
  __builtin_amdgcn_global_load_lds(
    (const __attribute__((address_space(1))) unsigned int*)g,
    (__attribute__((address_space(3))) unsigned int*)l, 16, 0, 0);
}

// ---------------- weight convert + transpose: f32 [K][N] -> bf16 [N][K] ----------------
static __device__ __forceinline__ void tr_body(u16 (*ld)[65],
    const float* __restrict__ in, u16* __restrict__ out, int K, int N)
{
  const int t = threadIdx.x;
  const int n0 = blockIdx.x * 64, k0 = blockIdx.y * 64;
  #pragma unroll
  for (int i = 0; i < 4; ++i){
    int idx = i*256 + t;
    int r = idx >> 4, c4 = (idx & 15) * 4;
    f32x4 v = *(const f32x4*)&in[(size_t)(k0 + r) * N + n0 + c4];
    ld[r][c4+0] = f2bf(v[0]); ld[r][c4+1] = f2bf(v[1]);
    ld[r][c4+2] = f2bf(v[2]); ld[r][c4+3] = f2bf(v[3]);
  }
  __syncthreads();
  #pragma unroll
  for (int i = 0; i < 4; ++i){
    int idx = i*256 + t;
    int c = idx >> 4, r4 = (idx & 15) * 4;
    u16x4 pk;
    pk[0]=ld[r4+0][c]; pk[1]=ld[r4+1][c]; pk[2]=ld[r4+2][c]; pk[3]=ld[r4+3][c];
    *(u16x4*)&out[(size_t)(n0 + c) * K + k0 + r4] = pk;
  }
}

__global__ __launch_bounds__(256) void transpose4_k(
    const float* __restrict__ i0, const float* __restrict__ i1,
    const float* __restrict__ i2, const float* __restrict__ i3,
    u16* __restrict__ o0, u16* __restrict__ o1, u16* __restrict__ o2, u16* __restrict__ o3)
{
  __shared__ u16 ld[64][65];
  int w = blockIdx.z >> 2, lyr = blockIdx.z & 3;
  const float* in = (w==0)?i0:(w==1)?i1:(w==2)?i2:i3;
  u16*      out = (w==0)?o0:(w==1)?o1:(w==2)?o2:o3;
  tr_body(ld, in + (size_t)lyr*DIM*DIM, out + (size_t)lyr*DIM*DIM, DIM, DIM);
}

__global__ __launch_bounds__(256) void transpose2_k(
    const float* __restrict__ i0, const float* __restrict__ i1,
    u16* __restrict__ o0, u16* __restrict__ o1)
{
  __shared__ u16 ld[64][65];
  int w = blockIdx.z >> 2, lyr = blockIdx.z & 3;
  const float* in = w ? i1 : i0;
  u16*      out = w ? o1 : o0;
  tr_body(ld, in + (size_t)lyr*DIM*HID, out + (size_t)lyr*DIM*HID, DIM, HID);
}

__global__ __launch_bounds__(256) void transpose1_k(
    const float* __restrict__ in, u16* __restrict__ out)
{
  __shared__ u16 ld[64][65];
  tr_body(ld, in + (size_t)blockIdx.z*HID*DIM, out + (size_t)blockIdx.z*HID*DIM, HID, DIM);
}

// ---------------- embedding gather ----------------
__global__ __launch_bounds__(256) void embed_k(const int* __restrict__ tok,
    const float* __restrict__ emb, float* __restrict__ h)
{
  int row = blockIdx.x;
  int t = tok[row];
  const f32x4* src = (const f32x4*)(emb + (size_t)t * DIM);
  f32x4* dst = (f32x4*)(h + (size_t)row * DIM);
  dst[threadIdx.x] = src[threadIdx.x];
}

// ---------------- RoPE cos/sin table ----------------
__global__ __launch_bounds__(256) void freqs_k(float* __restrict__ tab,
    const int* __restrict__ spp)
{
  int i = blockIdx.x * 256 + threadIdx.x;   // [0, S_LEN*32)
  int s = i >> 5, kk = i & 31;
  float inv = powf(10000.0f, -(float)kk * (1.0f/32.0f));
  float ang = (float)(*spp + s) * inv;
  tab[i*2]   = cosf(ang);
  tab[i*2+1] = sinf(ang);
}

// ---------------- RMSNorm -> bf16 ----------------
__global__ __launch_bounds__(256) void rmsnorm_k(const float* __restrict__ x,
    const float* __restrict__ w, u16* __restrict__ out)
{
  int row = blockIdx.x, t = threadIdx.x;
  const float* xr = x + (size_t)row * DIM;
  float v[4]; float ss = 0.f;
  #pragma unroll
  for (int i=0;i<4;i++){ v[i] = xr[t + 256*i]; ss += v[i]*v[i]; }
  #pragma unroll
  for (int o=1;o<64;o<<=1) ss += __shfl_xor(ss, o);
  __shared__ float red[4];
  if ((t & 63) == 0) red[t>>6] = ss;
  __syncthreads();
  float tot = red[0]+red[1]+red[2]+red[3];
  float rs = rsqrtf(tot * (1.0f/DIM) + 1e-6f);
  u16* orow = out + (size_t)row * DIM;
  #pragma unroll
  for (int i=0;i<4;i++) orow[t + 256*i] = f2bf(v[i]*rs*w[t+256*i]);
}

// RMSNorm of last-position rows -> f32
__global__ __launch_bounds__(256) void rmsnorm_last_k(const float* __restrict__ x,
    const float* __restrict__ w, float* __restrict__ out)
{
  int row = (blockIdx.x + 1) * S_LEN - 1;
  int t = threadIdx.x;
  const float* xr = x + (size_t)row * DIM;
  float v[4]; float ss = 0.f;
  #pragma unroll
  for (int i=0;i<4;i++){ v[i] = xr[t + 256*i]; ss += v[i]*v[i]; }
  #pragma unroll
  for (int o=1;o<64;o<<=1) ss += __shfl_xor(ss, o);
  __shared__ float red[4];
  if ((t & 63) == 0) red[t>>6] = ss;
  __syncthreads();
  float tot = red[0]+red[1]+red[2]+red[3];
  float rs = rsqrtf(tot * (1.0f/DIM) + 1e-6f);
  float* orow = out + (size_t)blockIdx.x * DIM;
  #pragma unroll
  for (int i=0;i<4;i++) orow[t + 256*i] = v[i]*rs*w[t+256*i];
}

// ---------------- pipelined GEMM, BK=64 (two BK=32 sub-stages), 2 buffers ----------------
// EPI: 1 = outF +=; 4 (NB=2) = outB = bf16(silu(acc0)*acc1);
//      5 = qkv epilogue: isv ? transposed V write [B,NH,HD,S] : RoPE -> outB
template<int EPI, int MT, int NT, int NB>
__device__ __forceinline__ void gemm_pipe(
    const u16* __restrict__ A, const u16* __restrict__ B1, const u16* __restrict__ B2,
    float* __restrict__ outF, u16* __restrict__ outB,
    const float* __restrict__ tab, int isv,
    int N, int K, int m0, int n0)
{
  constexpr int BM = MT*32, BN = NT*32;
  __shared__ __align__(16) u16 As[2][2*BM*32];
  __shared__ __align__(16) u16 Bs[2][2*NB*BN*32];
  const int t = threadIdx.x;
  const int lane = t & 63, wid = t >> 6;
  const int wm = wid >> 1, wn = wid & 1;
  const int l16 = lane & 15, lq = lane >> 4;
  const int srow = lane >> 2, scol = (lane & 3) * 8;
  const size_t rowK16 = (size_t)16 * K;

  const u16* ag  = A  + (size_t)(m0 + wid*(MT*8) + srow) * K + scol;
  const u16* bg1 = B1 + (size_t)(n0 + wid*(NT*8) + srow) * K + scol;
  const u16* bg2 = (NB == 2) ? (B2 + (size_t)(n0 + wid*(NT*8) + srow) * K + scol) : nullptr;

  f32x4 acc[NB][MT][NT];
  #pragma unroll
  for (int j=0;j<NB;j++)
    #pragma unroll
    for (int m=0;m<MT;m++)
      #pragma unroll
      for (int n=0;n<NT;n++) acc[j][m][n] = (f32x4){0.f,0.f,0.f,0.f};

  auto STAGE = [&](int buf, int k0){
    #pragma unroll
    for (int s = 0; s < 2; ++s){
      u16* al = &As[buf][(s*BM + wid*(MT*8))*32];
      #pragma unroll
      for (int pp = 0; pp < MT/2; ++pp)
        gload16(ag + s*32 + pp*rowK16 + k0, al + pp*512);
      u16* bl = &Bs[buf][(s*BN + wid*(NT*8))*32];
      #pragma unroll
      for (int pp = 0; pp < NT/2; ++pp)
        gload16(bg1 + s*32 + pp*rowK16 + k0, bl + pp*512);
      if (NB == 2) {
        u16* b2l = &Bs[buf][((2+s)*BN + wid*(NT*8))*32];
        #pragma unroll
        for (int pp = 0; pp < NT/2; ++pp)
          gload16(bg2 + s*32 + pp*rowK16 + k0, b2l + pp*512);
      }
    }
  };

  const int nt = K >> 6;
  STAGE(0, 0);
  __syncthreads();
  int cur = 0;
  for (int tt = 0; tt < nt; ++tt) {
    if (tt + 1 < nt) STAGE(cur ^ 1, (tt + 1) * 64);
    #pragma unroll
    for (int kk = 0; kk < 2; ++kk){
      short8 af[MT];
      #pragma unroll
      for (int m=0;m<MT;m++) af[m] = *(const short8*)&As[cur][(kk*BM + wm*(MT*16) + m*16 + l16)*32 + lq*8];
      #pragma unroll
      for (int j=0;j<NB;j++){
        short8 bfr[NT];
        #pragma unroll
        for (int n=0;n<NT;n++) bfr[n] = *(const short8*)&Bs[cur][((j*2+kk)*BN + wn*(NT*16) + n*16 + l16)*32 + lq*8];
        #pragma unroll
        for (int m=0;m<MT;m++)
          #pragma unroll
          for (int n=0;n<NT;n++)
            acc[j][m][n] = __builtin_amdgcn_mfma_f32_16x16x32_bf16(af[m], bfr[n], acc[j][m][n], 0, 0, 0);
      }
    }
    if (tt + 1 < nt) { __syncthreads(); cur ^= 1; }
  }

  #pragma unroll
  for (int m=0;m<MT;m++){
    int row = m0 + wm*(MT*16) + m*16 + lq*4;
    #pragma unroll
    for (int n=0;n<NT;n++){
      int col = n0 + wn*(NT*16) + n*16 + l16;
      if (EPI == 1){
        #pragma unroll
        for (int i=0;i<4;i++)
          outF[(size_t)(row+i)*N + col] += acc[0][m][n][i];
      } else if (EPI == 4){
        #pragma unroll
        for (int i=0;i<4;i++){
          float v1 = acc[0][m][n][i];
          float s = v1 / (1.0f + __expf(-v1));
          outB[(size_t)(row+i)*N + col] = f2bf(s * acc[1][m][n][i]);
        }
      } else if (EPI == 5){
        if (isv){
          int bidx = row >> 10, s0 = row & (S_LEN-1);
          int hh = col >> 6, d = col & 63;
          u16x4 pk;
          #pragma unroll
          for (int i=0;i<4;i++) pk[i] = f2bf(acc[0][m][n][i]);
          *(u16x4*)&outB[(((size_t)bidx*NH + hh)*HD + d)*S_LEN + s0] = pk;
        } else {
          int s0 = row & (S_LEN-1);
          int d = col & 63, kk2 = d >> 1;
          float sgn = (d & 1) ? 1.f : -1.f;
          #pragma unroll
          for (int i=0;i<4;i++){
            float val = acc[0][m][n][i];
            float par = __shfl_xor(val, 1);
            float c  = tab[((s0+i)*32 + kk2)*2];
            float sn = tab[((s0+i)*32 + kk2)*2 + 1];
            outB[(size_t)(row+i)*DIM + col] = f2bf(val*c + sgn*par*sn);
          }
        }
      }
    }
  }
}

template<int EPI, int MT, int NT>
__global__ __launch_bounds__(256) void gemm_k(const u16* __restrict__ A,
    const u16* __restrict__ Bt, float* __restrict__ outF,
    u16* __restrict__ outB, int N, int K)
{
  int nwg = gridDim.x * gridDim.y;
  int s = xcdswz(blockIdx.y * gridDim.x + blockIdx.x, nwg);
  int sx = s % gridDim.x, sy = s / gridDim.x;
  gemm_pipe<EPI,MT,NT,1>(A, Bt, nullptr, outF, outB, nullptr, 0, N, K,
                         sy*(MT*32), sx*(NT*32));
}

// fused FFN: g = bf16( silu(xn@w1) * (xn@w3) )  BM=64, BN=64 x2 (round-10 proven tile)
__global__ __launch_bounds__(256) void gemm_ffn13_k(const u16* __restrict__ A,
    const u16* __restrict__ W1t, const u16* __restrict__ W3t, u16* __restrict__ g)
{
  int nwg = gridDim.x * gridDim.y;
  int s = xcdswz(blockIdx.y * gridDim.x + blockIdx.x, nwg);
  int sx = s % gridDim.x, sy = s / gridDim.x;
  gemm_pipe<4,2,2,2>(A, W1t, W3t, nullptr, g, nullptr, 0, HID, DIM,
                     sy*64, sx*64);
}

// qkv + fused rope (q,k) / transposed write (v). BM=128, BN=64; grid.x = 48.
__global__ __launch_bounds__(256) void gemm_qkv_k(const u16* __restrict__ A,
    const u16* __restrict__ WqT, const u16* __restrict__ WkT, const u16* __restrict__ WvT,
    u16* __restrict__ q, u16* __restrict__ k, u16* __restrict__ vt,
    const float* __restrict__ tab)
{
  int nwg = gridDim.x * gridDim.y;
  int s = xcdswz(blockIdx.y * gridDim.x + blockIdx.x, nwg);
  int sx = s % gridDim.x, sy = s / gridDim.x;
  int which = sx >> 4;
  int n0 = (sx & 15) * 64;
  const u16* Bt = (which==0) ? WqT : (which==1 ? WkT : WvT);
  u16* o = (which==0) ? q : (which==1 ? k : vt);
  gemm_pipe<5,4,2,1>(A, Bt, nullptr, nullptr, o, tab, which==2, DIM, DIM,
                     sy*128, n0);
}

// ---------------- flash attention: swapped-operand + cooperative LDS dbuf, KVBLK=128 ----
// (round-10 best-measured form: eager rescale, __expf)
__global__ __launch_bounds__(256) void attn_k(const u16* __restrict__ Q,
    const u16* __restrict__ Kt, const u16* __restrict__ Vt,
    u16* __restrict__ O, const int* __restrict__ spp)
{
  __shared__ __align__(16) u16 Kl[2][128*64];
  __shared__ __align__(16) u16 Vl[2][64*128];
  const float NEG_INF = -__builtin_inff();
  int t = threadIdx.x, lane = t & 63, wid = t >> 6;
  int l16 = lane & 15, lq = lane >> 4;
  int nwg = gridDim.x * gridDim.y;
  int sblk = xcdswz(blockIdx.y * gridDim.x + blockIdx.x, nwg);
  int sx = sblk % gridDim.x, sy = sblk / gridDim.x;
  int q0b = sx * 64;
  int q0 = q0b + wid * 16;
  int b = sy >> 4, hh = sy & 15;
  int spos = *spp;
  const float scale = 0.125f;
  size_t bh = ((size_t)(b * S_LEN) * NH + hh) * HD;
  const u16* vtb = Vt + (size_t)sy * HD * S_LEN;  // [d][s]
  #define AOFF(s, d) (bh + (size_t)(s) * (NH*HD) + (d))

  short8 qf0 = *(const short8*)(Q + AOFF(q0 + l16, lq*8));
  short8 qf1 = *(const short8*)(Q + AOFF(q0 + l16, 32 + lq*8));

  f32x4 oa[4];
  #pragma unroll
  for (int j=0;j<4;j++) oa[j] = (f32x4){0.f,0.f,0.f,0.f};
  float m = NEG_INF, l = 0.f;
  int qrow = q0 + l16 + spos;
  int qmax = q0 + 15 + spos;                    // wave-uniform
  int nkb = q0b + 64 + spos; if (nkb > S_LEN) nkb = S_LEN;

  auto STAGE = [&](int buf, int kbs){
    #pragma unroll
    for (int p=0;p<4;p++){
      int kr = wid*32 + p*8 + (lane>>3);
      gload16(Kt + AOFF(kbs + kr, ((lane&7)^(lane>>3))*8), &Kl[buf][(wid*32 + p*8)*64]);
    }
    #pragma unroll
    for (int p=0;p<4;p++){
      int vr = wid*16 + p*4 + (lane>>4);
      gload16(vtb + (size_t)vr*S_LEN + kbs + (((lane&15)^(vr&7))*8), &Vl[buf][(wid*16 + p*4)*128]);
    }
  };

  STAGE(0, 0);
  __syncthreads();
  int cur = 0;
  for (int kb = 0; kb < nkb; kb += 128) {
    if (kb + 128 < nkb) STAGE(cur ^ 1, kb + 128);
    int ktmax = (qmax + 1 - kb + 15) >> 4; if (ktmax > 8) ktmax = 8;

    f32x4 s[8];
    __builtin_amdgcn_s_setprio(1);
    #pragma unroll
    for (int kt=0; kt<8; ++kt) if (kt < ktmax) {
      const u16* kr = &Kl[cur][(kt*16 + l16)*64];
      short8 kf0 = *(const short8*)(kr + (( lq      ^ (l16&7)) * 8));
      short8 kf1 = *(const short8*)(kr + (((4 + lq) ^ (l16&7)) * 8));
      f32x4 z = (f32x4){0.f,0.f,0.f,0.f};
      z = __builtin_amdgcn_mfma_f32_16x16x32_bf16(kf0, qf0, z, 0,0,0);
      z = __builtin_amdgcn_mfma_f32_16x16x32_bf16(kf1, qf1, z, 0,0,0);
      s[kt] = z;
    }
    __builtin_amdgcn_s_setprio(0);

    float p[32];
    #pragma unroll
    for (int kt=0; kt<8; ++kt)
      #pragma unroll
      for (int i=0;i<4;i++){
        int krow = kb + kt*16 + lq*4 + i;
        p[kt*4+i] = (kt < ktmax && krow <= qrow) ? s[kt][i]*scale : NEG_INF;
      }
    float pm = p[0];
    #pragma unroll
    for (int x=1;x<32;x++) pm = fmaxf(pm, p[x]);
    pm = fmaxf(pm, __shfl_xor(pm, 16));
    pm = fmaxf(pm, __shfl_xor(pm, 32));
    float mn = fmaxf(m, pm);
    float corr = __expf(m - mn);
    m = mn;
    float rs = 0.f;
    #pragma unroll
    for (int x=0;x<32;x++){ p[x] = __expf(p[x] - mn); rs += p[x]; }
    rs += __shfl_xor(rs, 16);
    rs += __shfl_xor(rs, 32);
    l = l*corr + rs;
    #pragma unroll
    for (int j=0;j<4;j++) oa[j] *= corr;

    __builtin_amdgcn_s_setprio(1);
    #pragma unroll
    for (int kt=0; kt<8; ++kt) if (kt < ktmax) {
      short4v pb;
      #pragma unroll
      for (int i=0;i<4;i++) pb[i] = (short)f2bf(p[kt*4+i]);
      #pragma unroll
      for (int j=0;j<4;j++){
        int rv = j*16 + l16;
        int ck = (kt*2 + (lq>>1)) ^ (l16&7);
        short4v va = *(const short4v*)(&Vl[cur][rv*128 + ck*8 + (lq&1)*4]);
        oa[j] = MFMA_PV(va, pb, oa[j]);
      }
    }
    __builtin_amdgcn_s_setprio(0);

    __syncthreads();
    cur ^= 1;
  }

  float inv = 1.0f / l;
  #pragma unroll
  for (int j=0;j<4;j++){
    u16x4 pk;
    #pragma unroll
    for (int i=0;i<4;i++) pk[i] = f2bf(oa[j][i] * inv);
    *(u16x4*)&O[AOFF(q0 + l16, j*16 + lq*4)] = pk;
  }
  #undef AOFF
}

// ---------------- final projection: [2,1024] @ [1024,32000] ----------------
__global__ __launch_bounds__(256) void outproj_k(const float* __restrict__ xf,
    const float* __restrict__ W, float* __restrict__ out)
{
  __shared__ float xs0[512], xs1[512];
  int t = threadIdx.x;
  int kbase = blockIdx.y * 512;
  for (int i = t; i < 512; i += 256){ xs0[i] = xf[kbase + i]; xs1[i] = xf[DIM + kbase + i]; }
  __syncthreads();
  int n = blockIdx.x * 256 + t;
  float a0 = 0.f, a1 = 0.f;
  #pragma unroll 8
  for (int k2 = 0; k2 < 512; ++k2){
    float w = W[(size_t)(kbase + k2) * NVOCAB + n];
    a0 += xs0[k2]*w; a1 += xs1[k2]*w;
  }
  atomicAdd(&out[n], a0);
  atomicAdd(&out[NVOCAB + n], a1);
}

extern "C" void kernel_launch(void* const* d_in, const int* in_sizes, int n_in,
                              void* d_out, int out_size, void* d_ws, size_t ws_size,
                              hipStream_t stream)
{
  const int*   tokens = (const int*)d_in[0];
  const int*   spp    = (const int*)d_in[1];
  const float* temb   = (const float*)d_in[2];
  const float* wq     = (const float*)d_in[3];
  const float* wk     = (const float*)d_in[4];
  const float* wv     = (const float*)d_in[5];
  const float* wo     = (const float*)d_in[6];
  const float* w1     = (const float*)d_in[7];
  const float* w2     = (const float*)d_in[8];
  const float* w3     = (const float*)d_in[9];
  const float* anw    = (const float*)d_in[10];
  const float* fnw    = (const float*)d_in[11];
  const float* finw   = (const float*)d_in[12];
  const float* outw   = (const float*)d_in[13];

  char* p = (char*)d_ws;
  auto carve = [&](size_t nbytes){ char* r = p; p += (nbytes + 255) & ~(size_t)255; return r; };
  const int R = B_SZ * S_LEN;  // 2048 rows
  float* h    = (float*)carve((size_t)R*DIM*4);
  u16* xn     = (u16*)carve((size_t)R*DIM*2);
  u16* qb     = (u16*)carve((size_t)R*DIM*2);
  u16* kb     = (u16*)carve((size_t)R*DIM*2);
  u16* vt     = (u16*)carve((size_t)R*DIM*2);
  u16* ob     = (u16*)carve((size_t)R*DIM*2);
  u16* g      = (u16*)carve((size_t)R*HID*2);
  float* tab  = (float*)carve((size_t)S_LEN*32*2*4);
  float* xfin = (float*)carve((size_t)B_SZ*DIM*4);
  // transposed bf16 weights
  u16* wqT = (u16*)carve((size_t)4*DIM*DIM*2);
  u16* wkT = (u16*)carve((size_t)4*DIM*DIM*2);
  u16* wvT = (u16*)carve((size_t)4*DIM*DIM*2);
  u16* woT = (u16*)carve((size_t)4*DIM*DIM*2);
  u16* w1T = (u16*)carve((size_t)4*DIM*HID*2);
  u16* w3T = (u16*)carve((size_t)4*DIM*HID*2);
  u16* w2T = (u16*)carve((size_t)4*HID*DIM*2);
  (void)ws_size; (void)in_sizes; (void)n_in;

  transpose4_k<<<dim3(16,16,16), 256, 0, stream>>>(wq, wk, wv, wo, wqT, wkT, wvT, woT);
  transpose2_k<<<dim3(44,16,8),  256, 0, stream>>>(w1, w3, w1T, w3T);
  transpose1_k<<<dim3(16,44,4),  256, 0, stream>>>(w2, w2T);

  freqs_k<<<(S_LEN*32)/256, 256, 0, stream>>>(tab, spp);
  embed_k<<<R, 256, 0, stream>>>(tokens, temb, h);

  for (int l = 0; l < 4; ++l) {
    size_t sqo = (size_t)l * DIM * DIM;
    size_t sff = (size_t)l * DIM * HID;
    rmsnorm_k<<<R, 256, 0, stream>>>(h, anw + l*DIM, xn);
    gemm_qkv_k<<<dim3(48, R/128), 256, 0, stream>>>(xn, wqT + sqo, wkT + sqo, wvT + sqo,
                                                    qb, kb, vt, tab);
    attn_k<<<dim3(S_LEN/64, B_SZ*NH), 256, 0, stream>>>(qb, kb, vt, ob, spp);
    gemm_k<1,2,2><<<dim3(DIM/64, R/64), 256, 0, stream>>>(ob, woT + sqo, h, nullptr, DIM, DIM);
    rmsnorm_k<<<R, 256, 0, stream>>>(h, fnw + l*DIM, xn);
    gemm_ffn13_k<<<dim3(HID/64, R/64), 256, 0, stream>>>(xn, w1T + sff, w3T + sff, g);
    gemm_k<1,2,2><<<dim3(DIM/64, R/64), 256, 0, stream>>>(g, w2T + sff, h, nullptr, DIM, HID);
  }
  rmsnorm_last_k<<<B_SZ, 256, 0, stream>>>(h, finw, xfin);
  hipMemsetAsync(d_out, 0, (size_t)out_size * sizeof(float), stream);
  outproj_k<<<dim3(NVOCAB/256, 2), 256, 0, stream>>>(xfin, outw, (float*)d_out);
}

// Round 14
// 700.488 us; speedup vs baseline: 1.1453x; 1.0207x over previous
//
#include <hip/hip_runtime.h>
#include <cstddef>

#define B_SZ 2
#define S_LEN 1024
#define NH 16
#define HD 64
#define DIM 1024
#define HID 2816
#define NVOCAB 32000

typedef __attribute__((ext_vector_type(8))) short short8;
typedef __attribute__((ext_vector_type(4))) short short4v;
typedef __attribute__((ext_vector_type(4))) float f32x4;
typedef __attribute__((ext_vector_type(4))) unsigned short u16x4;
typedef unsigned short u16;

#if __has_builtin(__builtin_amdgcn_mfma_f32_16x16x16_bf16)
#define MFMA_PV(a,b,c) __builtin_amdgcn_mfma_f32_16x16x16_bf16(a,b,c,0,0,0)
#else
#define MFMA_PV(a,b,c) __builtin_amdgcn_mfma_f32_16x16x16bf16_1k(a,b,c,0,0,0)
#endif

static __device__ __forceinline__ u16 f2bf(float f){
  unsigned u = __float_as_uint(f);
  u += 0x7FFFu + ((u >> 16) & 1u);   // RNE
  return (u16)(u >> 16);
}
static __device__ __forceinline__ float bf2f(unsigned u){
  return __uint_as_float(u << 16);
}

// XCD-aware bijective block remap (T1). Requires nwg % 8 == 0 (all our grids comply).
static __device__ __forceinline__ int xcdswz(int bid, int nwg){
  return (bid & 7) * (nwg >> 3) + (bid >> 3);
}

// async global->LDS, 16B per lane. LDS dest = wave-uniform base + lane*16 (linear).
static __device__ __forceinline__ void gload16(const void* g, void* l){
  __builtin_amdgcn_global_load_lds(
    (const __attribute__((address_space(1))) unsigned int*)g,
    (__attribute__((address_space(3))) unsigned int*)l, 16, 0, 0);
}

// ---------------- weight convert + transpose: f32 [K][N] -> bf16 [N][K] ----------------
static __device__ __forceinline__ void tr_body(u16 (*ld)[65],
    const float* __restrict__ in, u16* __restrict__ out, int K, int N)
{
  const int t = threadIdx.x;
  const int n0 = blockIdx.x * 64, k0 = blockIdx.y * 64;
  #pragma unroll
  for (int i = 0; i < 4; ++i){
    int idx = i*256 + t;
    int r = idx >> 4, c4 = (idx & 15) * 4;
    f32x4 v = *(const f32x4*)&in[(size_t)(k0 + r) * N + n0 + c4];
    ld[r][c4+0] = f2bf(v[0]); ld[r][c4+1] = f2bf(v[1]);
    ld[r][c4+2] = f2bf(v[2]); ld[r][c4+3] = f2bf(v[3]);
  }
  __syncthreads();
  #pragma unroll
  for (int i = 0; i < 4; ++i){
    int idx = i*256 + t;
    int c = idx >> 4, r4 = (idx & 15) * 4;
    u16x4 pk;
    pk[0]=ld[r4+0][c]; pk[1]=ld[r4+1][c]; pk[2]=ld[r4+2][c]; pk[3]=ld[r4+3][c];
    *(u16x4*)&out[(size_t)(n0 + c) * K + k0 + r4] = pk;
  }
}

__global__ __launch_bounds__(256) void transpose4_k(
    const float* __restrict__ i0, const float* __restrict__ i1,
    const float* __restrict__ i2, const float* __restrict__ i3,
    u16* __restrict__ o0, u16* __restrict__ o1, u16* __restrict__ o2, u16* __restrict__ o3)
{
  __shared__ u16 ld[64][65];
  int w = blockIdx.z >> 2, lyr = blockIdx.z & 3;
  const float* in = (w==0)?i0:(w==1)?i1:(w==2)?i2:i3;
  u16*      out = (w==0)?o0:(w==1)?o1:(w==2)?o2:o3;
  tr_body(ld, in + (size_t)lyr*DIM*DIM, out + (size_t)lyr*DIM*DIM, DIM, DIM);
}

__global__ __launch_bounds__(256) void transpose2_k(
    const float* __restrict__ i0, const float* __restrict__ i1,
    u16* __restrict__ o0, u16* __restrict__ o1)
{
  __shared__ u16 ld[64][65];
  int w = blockIdx.z >> 2, lyr = blockIdx.z & 3;
  const float* in = w ? i1 : i0;
  u16*      out = w ? o1 : o0;
  tr_body(ld, in + (size_t)lyr*DIM*HID, out + (size_t)lyr*DIM*HID, DIM, HID);
}

__global__ __launch_bounds__(256) void transpose1_k(
    const float* __restrict__ in, u16* __restrict__ out)
{
  __shared__ u16 ld[64][65];
  tr_body(ld, in + (size_t)blockIdx.z*HID*DIM, out + (size_t)blockIdx.z*HID*DIM, HID, DIM);
}

// ---------------- embedding gather ----------------
__global__ __launch_bounds__(256) void embed_k(const int* __restrict__ tok,
    const float* __restrict__ emb, float* __restrict__ h)
{
  int row = blockIdx.x;
  int t = tok[row];
  const f32x4* src = (const f32x4*)(emb + (size_t)t * DIM);
  f32x4* dst = (f32x4*)(h + (size_t)row * DIM);
  dst[threadIdx.x] = src[threadIdx.x];
}

// ---------------- RoPE cos/sin table ----------------
__global__ __launch_bounds__(256) void freqs_k(float* __restrict__ tab,
    const int* __restrict__ spp)
{
  int i = blockIdx.x * 256 + threadIdx.x;   // [0, S_LEN*32)
  int s = i >> 5, kk = i & 31;
  float inv = powf(10000.0f, -(float)kk * (1.0f/32.0f));
  float ang = (float)(*spp + s) * inv;
  tab[i*2]   = cosf(ang);
  tab[i*2+1] = sinf(ang);
}

// ---------------- RMSNorm -> bf16 ----------------
__global__ __launch_bounds__(256) void rmsnorm_k(const float* __restrict__ x,
    const float* __restrict__ w, u16* __restrict__ out)
{
  int row = blockIdx.x, t = threadIdx.x;
  const float* xr = x + (size_t)row * DIM;
  float v[4]; float ss = 0.f;
  #pragma unroll
  for (int i=0;i<4;i++){ v[i] = xr[t + 256*i]; ss += v[i]*v[i]; }
  #pragma unroll
  for (int o=1;o<64;o<<=1) ss += __shfl_xor(ss, o);
  __shared__ float red[4];
  if ((t & 63) == 0) red[t>>6] = ss;
  __syncthreads();
  float tot = red[0]+red[1]+red[2]+red[3];
  float rs = rsqrtf(tot * (1.0f/DIM) + 1e-6f);
  u16* orow = out + (size_t)row * DIM;
  #pragma unroll
  for (int i=0;i<4;i++) orow[t + 256*i] = f2bf(v[i]*rs*w[t+256*i]);
}

// RMSNorm of last-position rows -> f32
__global__ __launch_bounds__(256) void rmsnorm_last_k(const float* __restrict__ x,
    const float* __restrict__ w, float* __restrict__ out)
{
  int row = (blockIdx.x + 1) * S_LEN - 1;
  int t = threadIdx.x;
  const float* xr = x + (size_t)row * DIM;
  float v[4]; float ss = 0.f;
  #pragma unroll
  for (int i=0;i<4;i++){ v[i] = xr[t + 256*i]; ss += v[i]*v[i]; }
  #pragma unroll
  for (int o=1;o<64;o<<=1) ss += __shfl_xor(ss, o);
  __shared__ float red[4];
  if ((t & 63) == 0) red[t>>6] = ss;
  __syncthreads();
  float tot = red[0]+red[1]+red[2]+red[3];
  float rs = rsqrtf(tot * (1.0f/DIM) + 1e-6f);
  float* orow = out + (size_t)blockIdx.x * DIM;
  #pragma unroll
  for (int i=0;i<4;i++) orow[t + 256*i] = v[i]*rs*w[t+256*i];
}

// ---------------- pipelined GEMM, BK = NS*32 sub-stages, 2 buffers ----------------
// EPI: 1 = outF +=; 4 (NB=2) = outB = bf16(silu(acc0)*acc1);
//      5 = qkv epilogue: isv ? transposed V write [B,NH,HD,S] : RoPE -> outB
// NS: 32-wide K sub-stages per step. NS=4 (BK=128) halves barrier drains; only safe
// where occupancy is grid-limited (wo/w2: 512 blocks = 2/CU; LDS 64KB still fits 2/CU).
template<int EPI, int MT, int NT, int NB, int NS>
__device__ __forceinline__ void gemm_pipe(
    const u16* __restrict__ A, const u16* __restrict__ B1, const u16* __restrict__ B2,
    float* __restrict__ outF, u16* __restrict__ outB,
    const float* __restrict__ tab, int isv,
    int N, int K, int m0, int n0)
{
  constexpr int BM = MT*32, BN = NT*32;
  __shared__ __align__(16) u16 As[2][NS*BM*32];
  __shared__ __align__(16) u16 Bs[2][NS*NB*BN*32];
  const int t = threadIdx.x;
  const int lane = t & 63, wid = t >> 6;
  const int wm = wid >> 1, wn = wid & 1;
  const int l16 = lane & 15, lq = lane >> 4;
  const int srow = lane >> 2, scol = (lane & 3) * 8;
  const size_t rowK16 = (size_t)16 * K;

  const u16* ag  = A  + (size_t)(m0 + wid*(MT*8) + srow) * K + scol;
  const u16* bg1 = B1 + (size_t)(n0 + wid*(NT*8) + srow) * K + scol;
  const u16* bg2 = (NB == 2) ? (B2 + (size_t)(n0 + wid*(NT*8) + srow) * K + scol) : nullptr;

  f32x4 acc[NB][MT][NT];
  #pragma unroll
  for (int j=0;j<NB;j++)
    #pragma unroll
    for (int m=0;m<MT;m++)
      #pragma unroll
      for (int n=0;n<NT;n++) acc[j][m][n] = (f32x4){0.f,0.f,0.f,0.f};

  auto STAGE = [&](int buf, int k0){
    #pragma unroll
    for (int s = 0; s < NS; ++s){
      u16* al = &As[buf][(s*BM + wid*(MT*8))*32];
      #pragma unroll
      for (int pp = 0; pp < MT/2; ++pp)
        gload16(ag + s*32 + pp*rowK16 + k0, al + pp*512);
      u16* bl = &Bs[buf][(s*BN + wid*(NT*8))*32];
      #pragma unroll
      for (int pp = 0; pp < NT/2; ++pp)
        gload16(bg1 + s*32 + pp*rowK16 + k0, bl + pp*512);
      if (NB == 2) {
        u16* b2l = &Bs[buf][((NS+s)*BN + wid*(NT*8))*32];
        #pragma unroll
        for (int pp = 0; pp < NT/2; ++pp)
          gload16(bg2 + s*32 + pp*rowK16 + k0, b2l + pp*512);
      }
    }
  };

  const int nt = K / (NS*32);
  STAGE(0, 0);
  __syncthreads();
  int cur = 0;
  for (int tt = 0; tt < nt; ++tt) {
    if (tt + 1 < nt) STAGE(cur ^ 1, (tt + 1) * (NS*32));
    #pragma unroll
    for (int kk = 0; kk < NS; ++kk){
      short8 af[MT];
      #pragma unroll
      for (int m=0;m<MT;m++) af[m] = *(const short8*)&As[cur][(kk*BM + wm*(MT*16) + m*16 + l16)*32 + lq*8];
      #pragma unroll
      for (int j=0;j<NB;j++){
        short8 bfr[NT];
        #pragma unroll
        for (int n=0;n<NT;n++) bfr[n] = *(const short8*)&Bs[cur][((j*NS+kk)*BN + wn*(NT*16) + n*16 + l16)*32 + lq*8];
        #pragma unroll
        for (int m=0;m<MT;m++)
          #pragma unroll
          for (int n=0;n<NT;n++)
            acc[j][m][n] = __builtin_amdgcn_mfma_f32_16x16x32_bf16(af[m], bfr[n], acc[j][m][n], 0, 0, 0);
      }
    }
    if (tt + 1 < nt) { __syncthreads(); cur ^= 1; }
  }

  #pragma unroll
  for (int m=0;m<MT;m++){
    int row = m0 + wm*(MT*16) + m*16 + lq*4;
    #pragma unroll
    for (int n=0;n<NT;n++){
      int col = n0 + wn*(NT*16) + n*16 + l16;
      if (EPI == 1){
        #pragma unroll
        for (int i=0;i<4;i++)
          outF[(size_t)(row+i)*N + col] += acc[0][m][n][i];
      } else if (EPI == 4){
        #pragma unroll
        for (int i=0;i<4;i++){
          float v1 = acc[0][m][n][i];
          float s = v1 / (1.0f + __expf(-v1));
          outB[(size_t)(row+i)*N + col] = f2bf(s * acc[1][m][n][i]);
        }
      } else if (EPI == 5){
        if (isv){
          int bidx = row >> 10, s0 = row & (S_LEN-1);
          int hh = col >> 6, d = col & 63;
          u16x4 pk;
          #pragma unroll
          for (int i=0;i<4;i++) pk[i] = f2bf(acc[0][m][n][i]);
          *(u16x4*)&outB[(((size_t)bidx*NH + hh)*HD + d)*S_LEN + s0] = pk;
        } else {
          int s0 = row & (S_LEN-1);
          int d = col & 63, kk2 = d >> 1;
          float sgn = (d & 1) ? 1.f : -1.f;
          #pragma unroll
          for (int i=0;i<4;i++){
            float val = acc[0][m][n][i];
            float par = __shfl_xor(val, 1);
            float c  = tab[((s0+i)*32 + kk2)*2];
            float sn = tab[((s0+i)*32 + kk2)*2 + 1];
            outB[(size_t)(row+i)*DIM + col] = f2bf(val*c + sgn*par*sn);
          }
        }
      }
    }
  }
}

template<int EPI, int MT, int NT, int NS>
__global__ __launch_bounds__(256) void gemm_k(const u16* __restrict__ A,
    const u16* __restrict__ Bt, float* __restrict__ outF,
    u16* __restrict__ outB, int N, int K)
{
  int nwg = gridDim.x * gridDim.y;
  int s = xcdswz(blockIdx.y * gridDim.x + blockIdx.x, nwg);
  int sx = s % gridDim.x, sy = s / gridDim.x;
  gemm_pipe<EPI,MT,NT,1,NS>(A, Bt, nullptr, outF, outB, nullptr, 0, N, K,
                            sy*(MT*32), sx*(NT*32));
}

// fused FFN: g = bf16( silu(xn@w1) * (xn@w3) )  BM=64, BN=64 x2 (round-10 proven tile)
__global__ __launch_bounds__(256) void gemm_ffn13_k(const u16* __restrict__ A,
    const u16* __restrict__ W1t, const u16* __restrict__ W3t, u16* __restrict__ g)
{
  int nwg = gridDim.x * gridDim.y;
  int s = xcdswz(blockIdx.y * gridDim.x + blockIdx.x, nwg);
  int sx = s % gridDim.x, sy = s / gridDim.x;
  gemm_pipe<4,2,2,2,2>(A, W1t, W3t, nullptr, g, nullptr, 0, HID, DIM,
                       sy*64, sx*64);
}

// qkv + fused rope (q,k) / transposed write (v). BM=128, BN=64; grid.x = 48.
__global__ __launch_bounds__(256) void gemm_qkv_k(const u16* __restrict__ A,
    const u16* __restrict__ WqT, const u16* __restrict__ WkT, const u16* __restrict__ WvT,
    u16* __restrict__ q, u16* __restrict__ k, u16* __restrict__ vt,
    const float* __restrict__ tab)
{
  int nwg = gridDim.x * gridDim.y;
  int s = xcdswz(blockIdx.y * gridDim.x + blockIdx.x, nwg);
  int sx = s % gridDim.x, sy = s / gridDim.x;
  int which = sx >> 4;
  int n0 = (sx & 15) * 64;
  const u16* Bt = (which==0) ? WqT : (which==1 ? WkT : WvT);
  u16* o = (which==0) ? q : (which==1 ? k : vt);
  gemm_pipe<5,4,2,1,2>(A, Bt, nullptr, nullptr, o, tab, which==2, DIM, DIM,
                       sy*128, n0);
}

// ---------------- flash attention: swapped-operand + cooperative LDS dbuf, KVBLK=128 ----
// (round-10 best-measured form: eager rescale, __expf)
__global__ __launch_bounds__(256) void attn_k(const u16* __restrict__ Q,
    const u16* __restrict__ Kt, const u16* __restrict__ Vt,
    u16* __restrict__ O, const int* __restrict__ spp)
{
  __shared__ __align__(16) u16 Kl[2][128*64];
  __shared__ __align__(16) u16 Vl[2][64*128];
  const float NEG_INF = -__builtin_inff();
  int t = threadIdx.x, lane = t & 63, wid = t >> 6;
  int l16 = lane & 15, lq = lane >> 4;
  int nwg = gridDim.x * gridDim.y;
  int sblk = xcdswz(blockIdx.y * gridDim.x + blockIdx.x, nwg);
  int sx = sblk % gridDim.x, sy = sblk / gridDim.x;
  int q0b = sx * 64;
  int q0 = q0b + wid * 16;
  int b = sy >> 4, hh = sy & 15;
  int spos = *spp;
  const float scale = 0.125f;
  size_t bh = ((size_t)(b * S_LEN) * NH + hh) * HD;
  const u16* vtb = Vt + (size_t)sy * HD * S_LEN;  // [d][s]
  #define AOFF(s, d) (bh + (size_t)(s) * (NH*HD) + (d))

  short8 qf0 = *(const short8*)(Q + AOFF(q0 + l16, lq*8));
  short8 qf1 = *(const short8*)(Q + AOFF(q0 + l16, 32 + lq*8));

  f32x4 oa[4];
  #pragma unroll
  for (int j=0;j<4;j++) oa[j] = (f32x4){0.f,0.f,0.f,0.f};
  float m = NEG_INF, l = 0.f;
  int qrow = q0 + l16 + spos;
  int qmax = q0 + 15 + spos;                    // wave-uniform
  int nkb = q0b + 64 + spos; if (nkb > S_LEN) nkb = S_LEN;

  auto STAGE = [&](int buf, int kbs){
    #pragma unroll
    for (int p=0;p<4;p++){
      int kr = wid*32 + p*8 + (lane>>3);
      gload16(Kt + AOFF(kbs + kr, ((lane&7)^(lane>>3))*8), &Kl[buf][(wid*32 + p*8)*64]);
    }
    #pragma unroll
    for (int p=0;p<4;p++){
      int vr = wid*16 + p*4 + (lane>>4);
      gload16(vtb + (size_t)vr*S_LEN + kbs + (((lane&15)^(vr&7))*8), &Vl[buf][(wid*16 + p*4)*128]);
    }
  };

  STAGE(0, 0);
  __syncthreads();
  int cur = 0;
  for (int kb = 0; kb < nkb; kb += 128) {
    if (kb + 128 < nkb) STAGE(cur ^ 1, kb + 128);
    int ktmax = (qmax + 1 - kb + 15) >> 4; if (ktmax > 8) ktmax = 8;

    f32x4 s[8];
    __builtin_amdgcn_s_setprio(1);
    #pragma unroll
    for (int kt=0; kt<8; ++kt) if (kt < ktmax) {
      const u16* kr = &Kl[cur][(kt*16 + l16)*64];
      short8 kf0 = *(const short8*)(kr + (( lq      ^ (l16&7)) * 8));
      short8 kf1 = *(const short8*)(kr + (((4 + lq) ^ (l16&7)) * 8));
      f32x4 z = (f32x4){0.f,0.f,0.f,0.f};
      z = __builtin_amdgcn_mfma_f32_16x16x32_bf16(kf0, qf0, z, 0,0,0);
      z = __builtin_amdgcn_mfma_f32_16x16x32_bf16(kf1, qf1, z, 0,0,0);
      s[kt] = z;
    }
    __builtin_amdgcn_s_setprio(0);

    float p[32];
    #pragma unroll
    for (int kt=0; kt<8; ++kt)
      #pragma unroll
      for (int i=0;i<4;i++){
        int krow = kb + kt*16 + lq*4 + i;
        p[kt*4+i] = (kt < ktmax && krow <= qrow) ? s[kt][i]*scale : NEG_INF;
      }
    float pm = p[0];
    #pragma unroll
    for (int x=1;x<32;x++) pm = fmaxf(pm, p[x]);
    pm = fmaxf(pm, __shfl_xor(pm, 16));
    pm = fmaxf(pm, __shfl_xor(pm, 32));
    float mn = fmaxf(m, pm);
    float corr = __expf(m - mn);
    m = mn;
    float rs = 0.f;
    #pragma unroll
    for (int x=0;x<32;x++){ p[x] = __expf(p[x] - mn); rs += p[x]; }
    rs += __shfl_xor(rs, 16);
    rs += __shfl_xor(rs, 32);
    l = l*corr + rs;
    #pragma unroll
    for (int j=0;j<4;j++) oa[j] *= corr;

    __builtin_amdgcn_s_setprio(1);
    #pragma unroll
    for (int kt=0; kt<8; ++kt) if (kt < ktmax) {
      short4v pb;
      #pragma unroll
      for (int i=0;i<4;i++) pb[i] = (short)f2bf(p[kt*4+i]);
      #pragma unroll
      for (int j=0;j<4;j++){
        int rv = j*16 + l16;
        int ck = (kt*2 + (lq>>1)) ^ (l16&7);
        short4v va = *(const short4v*)(&Vl[cur][rv*128 + ck*8 + (lq&1)*4]);
        oa[j] = MFMA_PV(va, pb, oa[j]);
      }
    }
    __builtin_amdgcn_s_setprio(0);

    __syncthreads();
    cur ^= 1;
  }

  float inv = 1.0f / l;
  #pragma unroll
  for (int j=0;j<4;j++){
    u16x4 pk;
    #pragma unroll
    for (int i=0;i<4;i++) pk[i] = f2bf(oa[j][i] * inv);
    *(u16x4*)&O[AOFF(q0 + l16, j*16 + lq*4)] = pk;
  }
  #undef AOFF
}

// ---------------- final projection: [2,1024] @ [1024,32000] ----------------
__global__ __launch_bounds__(256) void outproj_k(const float* __restrict__ xf,
    const float* __restrict__ W, float* __restrict__ out)
{
  __shared__ float xs0[512], xs1[512];
  int t = threadIdx.x;
  int kbase = blockIdx.y * 512;
  for (int i = t; i < 512; i += 256){ xs0[i] = xf[kbase + i]; xs1[i] = xf[DIM + kbase + i]; }
  __syncthreads();
  int n = blockIdx.x * 256 + t;
  float a0 = 0.f, a1 = 0.f;
  #pragma unroll 8
  for (int k2 = 0; k2 < 512; ++k2){
    float w = W[(size_t)(kbase + k2) * NVOCAB + n];
    a0 += xs0[k2]*w; a1 += xs1[k2]*w;
  }
  atomicAdd(&out[n], a0);
  atomicAdd(&out[NVOCAB + n], a1);
}

extern "C" void kernel_launch(void* const* d_in, const int* in_sizes, int n_in,
                              void* d_out, int out_size, void* d_ws, size_t ws_size,
                              hipStream_t stream)
{
  const int*   tokens = (const int*)d_in[0];
  const int*   spp    = (const int*)d_in[1];
  const float* temb   = (const float*)d_in[2];
  const float* wq     = (const float*)d_in[3];
  const float* wk     = (const float*)d_in[4];
  const float* wv     = (const float*)d_in[5];
  const float* wo     = (const float*)d_in[6];
  const float* w1     = (const float*)d_in[7];
  const float* w2     = (const float*)d_in[8];
  const float* w3     = (const float*)d_in[9];
  const float* anw    = (const float*)d_in[10];
  const float* fnw    = (const float*)d_in[11];
  const float* finw   = (const float*)d_in[12];
  const float* outw   = (const float*)d_in[13];

  char* p = (char*)d_ws;
  auto carve = [&](size_t nbytes){ char* r = p; p += (nbytes + 255) & ~(size_t)255; return r; };
  const int R = B_SZ * S_LEN;  // 2048 rows
  float* h    = (float*)carve((size_t)R*DIM*4);
  u16* xn     = (u16*)carve((size_t)R*DIM*2);
  u16* qb     = (u16*)carve((size_t)R*DIM*2);
  u16* kb     = (u16*)carve((size_t)R*DIM*2);
  u16* vt     = (u16*)carve((size_t)R*DIM*2);
  u16* ob     = (u16*)carve((size_t)R*DIM*2);
  u16* g      = (u16*)carve((size_t)R*HID*2);
  float* tab  = (float*)carve((size_t)S_LEN*32*2*4);
  float* xfin = (float*)carve((size_t)B_SZ*DIM*4);
  // transposed bf16 weights
  u16* wqT = (u16*)carve((size_t)4*DIM*DIM*2);
  u16* wkT = (u16*)carve((size_t)4*DIM*DIM*2);
  u16* wvT = (u16*)carve((size_t)4*DIM*DIM*2);
  u16* woT = (u16*)carve((size_t)4*DIM*DIM*2);
  u16* w1T = (u16*)carve((size_t)4*DIM*HID*2);
  u16* w3T = (u16*)carve((size_t)4*DIM*HID*2);
  u16* w2T = (u16*)carve((size_t)4*HID*DIM*2);
  (void)ws_size; (void)in_sizes; (void)n_in;

  transpose4_k<<<dim3(16,16,16), 256, 0, stream>>>(wq, wk, wv, wo, wqT, wkT, wvT, woT);
  transpose2_k<<<dim3(44,16,8),  256, 0, stream>>>(w1, w3, w1T, w3T);
  transpose1_k<<<dim3(16,44,4),  256, 0, stream>>>(w2, w2T);

  freqs_k<<<(S_LEN*32)/256, 256, 0, stream>>>(tab, spp);
  embed_k<<<R, 256, 0, stream>>>(tokens, temb, h);

  for (int l = 0; l < 4; ++l) {
    size_t sqo = (size_t)l * DIM * DIM;
    size_t sff = (size_t)l * DIM * HID;
    rmsnorm_k<<<R, 256, 0, stream>>>(h, anw + l*DIM, xn);
    gemm_qkv_k<<<dim3(48, R/128), 256, 0, stream>>>(xn, wqT + sqo, wkT + sqo, wvT + sqo,
                                                    qb, kb, vt, tab);
    attn_k<<<dim3(S_LEN/64, B_SZ*NH), 256, 0, stream>>>(qb, kb, vt, ob, spp);
    gemm_k<1,2,2,4><<<dim3(DIM/64, R/64), 256, 0, stream>>>(ob, woT + sqo, h, nullptr, DIM, DIM);
    rmsnorm_k<<<R, 256, 0, stream>>>(h, fnw + l*DIM, xn);
    gemm_ffn13_k<<<dim3(HID/64, R/64), 256, 0, stream>>>(xn, w1T + sff, w3T + sff, g);
    gemm_k<1,2,2,4><<<dim3(DIM/64, R/64), 256, 0, stream>>>(g, w2T + sff, h, nullptr, DIM, HID);
  }
  rmsnorm_last_k<<<B_SZ, 256, 0, stream>>>(h, finw, xfin);
  hipMemsetAsync(d_out, 0, (size_t)out_size * sizeof(float), stream);
  outproj_k<<<dim3(NVOCAB/256, 2), 256, 0, stream>>>(xfin, outw, (float*)d_out);
}

// Round 15
// 688.851 us; speedup vs baseline: 1.1647x; 1.0169x over previous
//
#include <hip/hip_runtime.h>
#include <cstddef>

#define B_SZ 2
#define S_LEN 1024
#define NH 16
#define HD 64
#define DIM 1024
#define HID 2816
#define NVOCAB 32000

typedef __attribute__((ext_vector_type(8))) short short8;
typedef __attribute__((ext_vector_type(4))) short short4v;
typedef __attribute__((ext_vector_type(4))) float f32x4;
typedef __attribute__((ext_vector_type(4))) unsigned short u16x4;
typedef unsigned short u16;

#if __has_builtin(__builtin_amdgcn_mfma_f32_16x16x16_bf16)
#define MFMA_PV(a,b,c) __builtin_amdgcn_mfma_f32_16x16x16_bf16(a,b,c,0,0,0)
#else
#define MFMA_PV(a,b,c) __builtin_amdgcn_mfma_f32_16x16x16bf16_1k(a,b,c,0,0,0)
#endif

static __device__ __forceinline__ u16 f2bf(float f){
  unsigned u = __float_as_uint(f);
  u += 0x7FFFu + ((u >> 16) & 1u);   // RNE
  return (u16)(u >> 16);
}
static __device__ __forceinline__ float bf2f(unsigned u){
  return __uint_as_float(u << 16);
}

// XCD-aware bijective block remap (T1). Requires nwg % 8 == 0 (all our grids comply).
static __device__ __forceinline__ int xcdswz(int bid, int nwg){
  return (bid & 7) * (nwg >> 3) + (bid >> 3);
}

// async global->LDS, 16B per lane. LDS dest = wave-uniform base + lane*16 (linear).
static __device__ __forceinline__ void gload16(const void* g, void* l){
  __builtin_amdgcn_global_load_lds(
    (const __attribute__((address_space(1))) unsigned int*)g,
    (__attribute__((address_space(3))) unsigned int*)l, 16, 0, 0);
}

// ---------------- weight convert + transpose: f32 [K][N] -> bf16 [N][K] ----------------
static __device__ __forceinline__ void tr_body(u16 (*ld)[65],
    const float* __restrict__ in, u16* __restrict__ out, int K, int N)
{
  const int t = threadIdx.x;
  const int n0 = blockIdx.x * 64, k0 = blockIdx.y * 64;
  #pragma unroll
  for (int i = 0; i < 4; ++i){
    int idx = i*256 + t;
    int r = idx >> 4, c4 = (idx & 15) * 4;
    f32x4 v = *(const f32x4*)&in[(size_t)(k0 + r) * N + n0 + c4];
    ld[r][c4+0] = f2bf(v[0]); ld[r][c4+1] = f2bf(v[1]);
    ld[r][c4+2] = f2bf(v[2]); ld[r][c4+3] = f2bf(v[3]);
  }
  __syncthreads();
  #pragma unroll
  for (int i = 0; i < 4; ++i){
    int idx = i*256 + t;
    int c = idx >> 4, r4 = (idx & 15) * 4;
    u16x4 pk;
    pk[0]=ld[r4+0][c]; pk[1]=ld[r4+1][c]; pk[2]=ld[r4+2][c]; pk[3]=ld[r4+3][c];
    *(u16x4*)&out[(size_t)(n0 + c) * K + k0 + r4] = pk;
  }
}

__global__ __launch_bounds__(256) void transpose4_k(
    const float* __restrict__ i0, const float* __restrict__ i1,
    const float* __restrict__ i2, const float* __restrict__ i3,
    u16* __restrict__ o0, u16* __restrict__ o1, u16* __restrict__ o2, u16* __restrict__ o3)
{
  __shared__ u16 ld[64][65];
  int w = blockIdx.z >> 2, lyr = blockIdx.z & 3;
  const float* in = (w==0)?i0:(w==1)?i1:(w==2)?i2:i3;
  u16*      out = (w==0)?o0:(w==1)?o1:(w==2)?o2:o3;
  tr_body(ld, in + (size_t)lyr*DIM*DIM, out + (size_t)lyr*DIM*DIM, DIM, DIM);
}

__global__ __launch_bounds__(256) void transpose2_k(
    const float* __restrict__ i0, const float* __restrict__ i1,
    u16* __restrict__ o0, u16* __restrict__ o1)
{
  __shared__ u16 ld[64][65];
  int w = blockIdx.z >> 2, lyr = blockIdx.z & 3;
  const float* in = w ? i1 : i0;
  u16*      out = w ? o1 : o0;
  tr_body(ld, in + (size_t)lyr*DIM*HID, out + (size_t)lyr*DIM*HID, DIM, HID);
}

__global__ __launch_bounds__(256) void transpose1_k(
    const float* __restrict__ in, u16* __restrict__ out)
{
  __shared__ u16 ld[64][65];
  tr_body(ld, in + (size_t)blockIdx.z*HID*DIM, out + (size_t)blockIdx.z*HID*DIM, HID, DIM);
}

// ---------------- embedding gather ----------------
__global__ __launch_bounds__(256) void embed_k(const int* __restrict__ tok,
    const float* __restrict__ emb, float* __restrict__ h)
{
  int row = blockIdx.x;
  int t = tok[row];
  const f32x4* src = (const f32x4*)(emb + (size_t)t * DIM);
  f32x4* dst = (f32x4*)(h + (size_t)row * DIM);
  dst[threadIdx.x] = src[threadIdx.x];
}

// ---------------- RoPE cos/sin table ----------------
__global__ __launch_bounds__(256) void freqs_k(float* __restrict__ tab,
    const int* __restrict__ spp)
{
  int i = blockIdx.x * 256 + threadIdx.x;   // [0, S_LEN*32)
  int s = i >> 5, kk = i & 31;
  float inv = powf(10000.0f, -(float)kk * (1.0f/32.0f));
  float ang = (float)(*spp + s) * inv;
  tab[i*2]   = cosf(ang);
  tab[i*2+1] = sinf(ang);
}

// ---------------- RMSNorm -> bf16 ----------------
__global__ __launch_bounds__(256) void rmsnorm_k(const float* __restrict__ x,
    const float* __restrict__ w, u16* __restrict__ out)
{
  int row = blockIdx.x, t = threadIdx.x;
  const float* xr = x + (size_t)row * DIM;
  float v[4]; float ss = 0.f;
  #pragma unroll
  for (int i=0;i<4;i++){ v[i] = xr[t + 256*i]; ss += v[i]*v[i]; }
  #pragma unroll
  for (int o=1;o<64;o<<=1) ss += __shfl_xor(ss, o);
  __shared__ float red[4];
  if ((t & 63) == 0) red[t>>6] = ss;
  __syncthreads();
  float tot = red[0]+red[1]+red[2]+red[3];
  float rs = rsqrtf(tot * (1.0f/DIM) + 1e-6f);
  u16* orow = out + (size_t)row * DIM;
  #pragma unroll
  for (int i=0;i<4;i++) orow[t + 256*i] = f2bf(v[i]*rs*w[t+256*i]);
}

// RMSNorm of last-position rows -> f32
__global__ __launch_bounds__(256) void rmsnorm_last_k(const float* __restrict__ x,
    const float* __restrict__ w, float* __restrict__ out)
{
  int row = (blockIdx.x + 1) * S_LEN - 1;
  int t = threadIdx.x;
  const float* xr = x + (size_t)row * DIM;
  float v[4]; float ss = 0.f;
  #pragma unroll
  for (int i=0;i<4;i++){ v[i] = xr[t + 256*i]; ss += v[i]*v[i]; }
  #pragma unroll
  for (int o=1;o<64;o<<=1) ss += __shfl_xor(ss, o);
  __shared__ float red[4];
  if ((t & 63) == 0) red[t>>6] = ss;
  __syncthreads();
  float tot = red[0]+red[1]+red[2]+red[3];
  float rs = rsqrtf(tot * (1.0f/DIM) + 1e-6f);
  float* orow = out + (size_t)blockIdx.x * DIM;
  #pragma unroll
  for (int i=0;i<4;i++) orow[t + 256*i] = v[i]*rs*w[t+256*i];
}

// ---------------- pipelined GEMM, BK = NS*32 sub-stages, 2 buffers ----------------
// EPI: 1 = outF +=; 4 (NB=2) = outB = bf16(silu(acc0)*acc1);
//      5 = qkv epilogue: isv ? transposed V write [B,NH,HD,S] : RoPE -> outB
// NS: 32-wide K sub-stages per step. NS=4 (BK=128) where grid-limited (wo/w2, 2/CU);
// NS=1 (BK=32, 24KB LDS) where grid offers >3/CU so occupancy pays (ffn13: 5.5/CU).
template<int EPI, int MT, int NT, int NB, int NS>
__device__ __forceinline__ void gemm_pipe(
    const u16* __restrict__ A, const u16* __restrict__ B1, const u16* __restrict__ B2,
    float* __restrict__ outF, u16* __restrict__ outB,
    const float* __restrict__ tab, int isv,
    int N, int K, int m0, int n0)
{
  constexpr int BM = MT*32, BN = NT*32;
  __shared__ __align__(16) u16 As[2][NS*BM*32];
  __shared__ __align__(16) u16 Bs[2][NS*NB*BN*32];
  const int t = threadIdx.x;
  const int lane = t & 63, wid = t >> 6;
  const int wm = wid >> 1, wn = wid & 1;
  const int l16 = lane & 15, lq = lane >> 4;
  const int srow = lane >> 2, scol = (lane & 3) * 8;
  const size_t rowK16 = (size_t)16 * K;

  const u16* ag  = A  + (size_t)(m0 + wid*(MT*8) + srow) * K + scol;
  const u16* bg1 = B1 + (size_t)(n0 + wid*(NT*8) + srow) * K + scol;
  const u16* bg2 = (NB == 2) ? (B2 + (size_t)(n0 + wid*(NT*8) + srow) * K + scol) : nullptr;

  f32x4 acc[NB][MT][NT];
  #pragma unroll
  for (int j=0;j<NB;j++)
    #pragma unroll
    for (int m=0;m<MT;m++)
      #pragma unroll
      for (int n=0;n<NT;n++) acc[j][m][n] = (f32x4){0.f,0.f,0.f,0.f};

  auto STAGE = [&](int buf, int k0){
    #pragma unroll
    for (int s = 0; s < NS; ++s){
      u16* al = &As[buf][(s*BM + wid*(MT*8))*32];
      #pragma unroll
      for (int pp = 0; pp < MT/2; ++pp)
        gload16(ag + s*32 + pp*rowK16 + k0, al + pp*512);
      u16* bl = &Bs[buf][(s*BN + wid*(NT*8))*32];
      #pragma unroll
      for (int pp = 0; pp < NT/2; ++pp)
        gload16(bg1 + s*32 + pp*rowK16 + k0, bl + pp*512);
      if (NB == 2) {
        u16* b2l = &Bs[buf][((NS+s)*BN + wid*(NT*8))*32];
        #pragma unroll
        for (int pp = 0; pp < NT/2; ++pp)
          gload16(bg2 + s*32 + pp*rowK16 + k0, b2l + pp*512);
      }
    }
  };

  const int nt = K / (NS*32);
  STAGE(0, 0);
  __syncthreads();
  int cur = 0;
  for (int tt = 0; tt < nt; ++tt) {
    if (tt + 1 < nt) STAGE(cur ^ 1, (tt + 1) * (NS*32));
    #pragma unroll
    for (int kk = 0; kk < NS; ++kk){
      short8 af[MT];
      #pragma unroll
      for (int m=0;m<MT;m++) af[m] = *(const short8*)&As[cur][(kk*BM + wm*(MT*16) + m*16 + l16)*32 + lq*8];
      #pragma unroll
      for (int j=0;j<NB;j++){
        short8 bfr[NT];
        #pragma unroll
        for (int n=0;n<NT;n++) bfr[n] = *(const short8*)&Bs[cur][((j*NS+kk)*BN + wn*(NT*16) + n*16 + l16)*32 + lq*8];
        #pragma unroll
        for (int m=0;m<MT;m++)
          #pragma unroll
          for (int n=0;n<NT;n++)
            acc[j][m][n] = __builtin_amdgcn_mfma_f32_16x16x32_bf16(af[m], bfr[n], acc[j][m][n], 0, 0, 0);
      }
    }
    if (tt + 1 < nt) { __syncthreads(); cur ^= 1; }
  }

  #pragma unroll
  for (int m=0;m<MT;m++){
    int row = m0 + wm*(MT*16) + m*16 + lq*4;
    #pragma unroll
    for (int n=0;n<NT;n++){
      int col = n0 + wn*(NT*16) + n*16 + l16;
      if (EPI == 1){
        #pragma unroll
        for (int i=0;i<4;i++)
          outF[(size_t)(row+i)*N + col] += acc[0][m][n][i];
      } else if (EPI == 4){
        #pragma unroll
        for (int i=0;i<4;i++){
          float v1 = acc[0][m][n][i];
          float s = v1 / (1.0f + __expf(-v1));
          outB[(size_t)(row+i)*N + col] = f2bf(s * acc[1][m][n][i]);
        }
      } else if (EPI == 5){
        if (isv){
          int bidx = row >> 10, s0 = row & (S_LEN-1);
          int hh = col >> 6, d = col & 63;
          u16x4 pk;
          #pragma unroll
          for (int i=0;i<4;i++) pk[i] = f2bf(acc[0][m][n][i]);
          *(u16x4*)&outB[(((size_t)bidx*NH + hh)*HD + d)*S_LEN + s0] = pk;
        } else {
          int s0 = row & (S_LEN-1);
          int d = col & 63, kk2 = d >> 1;
          float sgn = (d & 1) ? 1.f : -1.f;
          #pragma unroll
          for (int i=0;i<4;i++){
            float val = acc[0][m][n][i];
            float par = __shfl_xor(val, 1);
            float c  = tab[((s0+i)*32 + kk2)*2];
            float sn = tab[((s0+i)*32 + kk2)*2 + 1];
            outB[(size_t)(row+i)*DIM + col] = f2bf(val*c + sgn*par*sn);
          }
        }
      }
    }
  }
}

template<int EPI, int MT, int NT, int NS>
__global__ __launch_bounds__(256) void gemm_k(const u16* __restrict__ A,
    const u16* __restrict__ Bt, float* __restrict__ outF,
    u16* __restrict__ outB, int N, int K)
{
  int nwg = gridDim.x * gridDim.y;
  int s = xcdswz(blockIdx.y * gridDim.x + blockIdx.x, nwg);
  int sx = s % gridDim.x, sy = s / gridDim.x;
  gemm_pipe<EPI,MT,NT,1,NS>(A, Bt, nullptr, outF, outB, nullptr, 0, N, K,
                            sy*(MT*32), sx*(NT*32));
}

// fused FFN: g = bf16( silu(xn@w1) * (xn@w3) )  BM=64, BN=64 x2, NS=1 (24KB LDS ->
// occupancy grid-limited at 5.5 blocks/CU; trades barrier amortization for TLP)
__global__ __launch_bounds__(256) void gemm_ffn13_k(const u16* __restrict__ A,
    const u16* __restrict__ W1t, const u16* __restrict__ W3t, u16* __restrict__ g)
{
  int nwg = gridDim.x * gridDim.y;
  int s = xcdswz(blockIdx.y * gridDim.x + blockIdx.x, nwg);
  int sx = s % gridDim.x, sy = s / gridDim.x;
  gemm_pipe<4,2,2,2,1>(A, W1t, W3t, nullptr, g, nullptr, 0, HID, DIM,
                       sy*64, sx*64);
}

// qkv + fused rope (q,k) / transposed write (v). BM=128, BN=64; grid.x = 48.
__global__ __launch_bounds__(256) void gemm_qkv_k(const u16* __restrict__ A,
    const u16* __restrict__ WqT, const u16* __restrict__ WkT, const u16* __restrict__ WvT,
    u16* __restrict__ q, u16* __restrict__ k, u16* __restrict__ vt,
    const float* __restrict__ tab)
{
  int nwg = gridDim.x * gridDim.y;
  int s = xcdswz(blockIdx.y * gridDim.x + blockIdx.x, nwg);
  int sx = s % gridDim.x, sy = s / gridDim.x;
  int which = sx >> 4;
  int n0 = (sx & 15) * 64;
  const u16* Bt = (which==0) ? WqT : (which==1 ? WkT : WvT);
  u16* o = (which==0) ? q : (which==1 ? k : vt);
  gemm_pipe<5,4,2,1,2>(A, Bt, nullptr, nullptr, o, tab, which==2, DIM, DIM,
                       sy*128, n0);
}

// ---------------- flash attention: swapped-operand + cooperative LDS dbuf, KVBLK=128 ----
// (round-10 best-measured form: eager rescale, __expf)
__global__ __launch_bounds__(256) void attn_k(const u16* __restrict__ Q,
    const u16* __restrict__ Kt, const u16* __restrict__ Vt,
    u16* __restrict__ O, const int* __restrict__ spp)
{
  __shared__ __align__(16) u16 Kl[2][128*64];
  __shared__ __align__(16) u16 Vl[2][64*128];
  const float NEG_INF = -__builtin_inff();
  int t = threadIdx.x, lane = t & 63, wid = t >> 6;
  int l16 = lane & 15, lq = lane >> 4;
  int nwg = gridDim.x * gridDim.y;
  int sblk = xcdswz(blockIdx.y * gridDim.x + blockIdx.x, nwg);
  int sx = sblk % gridDim.x, sy = sblk / gridDim.x;
  int q0b = sx * 64;
  int q0 = q0b + wid * 16;
  int b = sy >> 4, hh = sy & 15;
  int spos = *spp;
  const float scale = 0.125f;
  size_t bh = ((size_t)(b * S_LEN) * NH + hh) * HD;
  const u16* vtb = Vt + (size_t)sy * HD * S_LEN;  // [d][s]
  #define AOFF(s, d) (bh + (size_t)(s) * (NH*HD) + (d))

  short8 qf0 = *(const short8*)(Q + AOFF(q0 + l16, lq*8));
  short8 qf1 = *(const short8*)(Q + AOFF(q0 + l16, 32 + lq*8));

  f32x4 oa[4];
  #pragma unroll
  for (int j=0;j<4;j++) oa[j] = (f32x4){0.f,0.f,0.f,0.f};
  float m = NEG_INF, l = 0.f;
  int qrow = q0 + l16 + spos;
  int qmax = q0 + 15 + spos;                    // wave-uniform
  int nkb = q0b + 64 + spos; if (nkb > S_LEN) nkb = S_LEN;

  auto STAGE = [&](int buf, int kbs){
    #pragma unroll
    for (int p=0;p<4;p++){
      int kr = wid*32 + p*8 + (lane>>3);
      gload16(Kt + AOFF(kbs + kr, ((lane&7)^(lane>>3))*8), &Kl[buf][(wid*32 + p*8)*64]);
    }
    #pragma unroll
    for (int p=0;p<4;p++){
      int vr = wid*16 + p*4 + (lane>>4);
      gload16(vtb + (size_t)vr*S_LEN + kbs + (((lane&15)^(vr&7))*8), &Vl[buf][(wid*16 + p*4)*128]);
    }
  };

  STAGE(0, 0);
  __syncthreads();
  int cur = 0;
  for (int kb = 0; kb < nkb; kb += 128) {
    if (kb + 128 < nkb) STAGE(cur ^ 1, kb + 128);
    int ktmax = (qmax + 1 - kb + 15) >> 4; if (ktmax > 8) ktmax = 8;

    f32x4 s[8];
    __builtin_amdgcn_s_setprio(1);
    #pragma unroll
    for (int kt=0; kt<8; ++kt) if (kt < ktmax) {
      const u16* kr = &Kl[cur][(kt*16 + l16)*64];
      short8 kf0 = *(const short8*)(kr + (( lq      ^ (l16&7)) * 8));
      short8 kf1 = *(const short8*)(kr + (((4 + lq) ^ (l16&7)) * 8));
      f32x4 z = (f32x4){0.f,0.f,0.f,0.f};
      z = __builtin_amdgcn_mfma_f32_16x16x32_bf16(kf0, qf0, z, 0,0,0);
      z = __builtin_amdgcn_mfma_f32_16x16x32_bf16(kf1, qf1, z, 0,0,0);
      s[kt] = z;
    }
    __builtin_amdgcn_s_setprio(0);

    float p[32];
    #pragma unroll
    for (int kt=0; kt<8; ++kt)
      #pragma unroll
      for (int i=0;i<4;i++){
        int krow = kb + kt*16 + lq*4 + i;
        p[kt*4+i] = (kt < ktmax && krow <= qrow) ? s[kt][i]*scale : NEG_INF;
      }
    float pm = p[0];
    #pragma unroll
    for (int x=1;x<32;x++) pm = fmaxf(pm, p[x]);
    pm = fmaxf(pm, __shfl_xor(pm, 16));
    pm = fmaxf(pm, __shfl_xor(pm, 32));
    float mn = fmaxf(m, pm);
    float corr = __expf(m - mn);
    m = mn;
    float rs = 0.f;
    #pragma unroll
    for (int x=0;x<32;x++){ p[x] = __expf(p[x] - mn); rs += p[x]; }
    rs += __shfl_xor(rs, 16);
    rs += __shfl_xor(rs, 32);
    l = l*corr + rs;
    #pragma unroll
    for (int j=0;j<4;j++) oa[j] *= corr;

    __builtin_amdgcn_s_setprio(1);
    #pragma unroll
    for (int kt=0; kt<8; ++kt) if (kt < ktmax) {
      short4v pb;
      #pragma unroll
      for (int i=0;i<4;i++) pb[i] = (short)f2bf(p[kt*4+i]);
      #pragma unroll
      for (int j=0;j<4;j++){
        int rv = j*16 + l16;
        int ck = (kt*2 + (lq>>1)) ^ (l16&7);
        short4v va = *(const short4v*)(&Vl[cur][rv*128 + ck*8 + (lq&1)*4]);
        oa[j] = MFMA_PV(va, pb, oa[j]);
      }
    }
    __builtin_amdgcn_s_setprio(0);

    __syncthreads();
    cur ^= 1;
  }

  float inv = 1.0f / l;
  #pragma unroll
  for (int j=0;j<4;j++){
    u16x4 pk;
    #pragma unroll
    for (int i=0;i<4;i++) pk[i] = f2bf(oa[j][i] * inv);
    *(u16x4*)&O[AOFF(q0 + l16, j*16 + lq*4)] = pk;
  }
  #undef AOFF
}

// ---------------- final projection: [2,1024] @ [1024,32000] ----------------
__global__ __launch_bounds__(256) void outproj_k(const float* __restrict__ xf,
    const float* __restrict__ W, float* __restrict__ out)
{
  __shared__ float xs0[512], xs1[512];
  int t = threadIdx.x;
  int kbase = blockIdx.y * 512;
  for (int i = t; i < 512; i += 256){ xs0[i] = xf[kbase + i]; xs1[i] = xf[DIM + kbase + i]; }
  __syncthreads();
  int n = blockIdx.x * 256 + t;
  float a0 = 0.f, a1 = 0.f;
  #pragma unroll 8
  for (int k2 = 0; k2 < 512; ++k2){
    float w = W[(size_t)(kbase + k2) * NVOCAB + n];
    a0 += xs0[k2]*w; a1 += xs1[k2]*w;
  }
  atomicAdd(&out[n], a0);
  atomicAdd(&out[NVOCAB + n], a1);
}

extern "C" void kernel_launch(void* const* d_in, const int* in_sizes, int n_in,
                              void* d_out, int out_size, void* d_ws, size_t ws_size,
                              hipStream_t stream)
{
  const int*   tokens = (const int*)d_in[0];
  const int*   spp    = (const int*)d_in[1];
  const float* temb   = (const float*)d_in[2];
  const float* wq     = (const float*)d_in[3];
  const float* wk     = (const float*)d_in[4];
  const float* wv     = (const float*)d_in[5];
  const float* wo     = (const float*)d_in[6];
  const float* w1     = (const float*)d_in[7];
  const float* w2     = (const float*)d_in[8];
  const float* w3     = (const float*)d_in[9];
  const float* anw    = (const float*)d_in[10];
  const float* fnw    = (const float*)d_in[11];
  const float* finw   = (const float*)d_in[12];
  const float* outw   = (const float*)d_in[13];

  char* p = (char*)d_ws;
  auto carve = [&](size_t nbytes){ char* r = p; p += (nbytes + 255) & ~(size_t)255; return r; };
  const int R = B_SZ * S_LEN;  // 2048 rows
  float* h    = (float*)carve((size_t)R*DIM*4);
  u16* xn     = (u16*)carve((size_t)R*DIM*2);
  u16* qb     = (u16*)carve((size_t)R*DIM*2);
  u16* kb     = (u16*)carve((size_t)R*DIM*2);
  u16* vt     = (u16*)carve((size_t)R*DIM*2);
  u16* ob     = (u16*)carve((size_t)R*DIM*2);
  u16* g      = (u16*)carve((size_t)R*HID*2);
  float* tab  = (float*)carve((size_t)S_LEN*32*2*4);
  float* xfin = (float*)carve((size_t)B_SZ*DIM*4);
  // transposed bf16 weights
  u16* wqT = (u16*)carve((size_t)4*DIM*DIM*2);
  u16* wkT = (u16*)carve((size_t)4*DIM*DIM*2);
  u16* wvT = (u16*)carve((size_t)4*DIM*DIM*2);
  u16* woT = (u16*)carve((size_t)4*DIM*DIM*2);
  u16* w1T = (u16*)carve((size_t)4*DIM*HID*2);
  u16* w3T = (u16*)carve((size_t)4*DIM*HID*2);
  u16* w2T = (u16*)carve((size_t)4*HID*DIM*2);
  (void)ws_size; (void)in_sizes; (void)n_in;

  transpose4_k<<<dim3(16,16,16), 256, 0, stream>>>(wq, wk, wv, wo, wqT, wkT, wvT, woT);
  transpose2_k<<<dim3(44,16,8),  256, 0, stream>>>(w1, w3, w1T, w3T);
  transpose1_k<<<dim3(16,44,4),  256, 0, stream>>>(w2, w2T);

  freqs_k<<<(S_LEN*32)/256, 256, 0, stream>>>(tab, spp);
  embed_k<<<R, 256, 0, stream>>>(tokens, temb, h);

  for (int l = 0; l < 4; ++l) {
    size_t sqo = (size_t)l * DIM * DIM;
    size_t sff = (size_t)l * DIM * HID;
    rmsnorm_k<<<R, 256, 0, stream>>>(h, anw + l*DIM, xn);
    gemm_qkv_k<<<dim3(48, R/128), 256, 0, stream>>>(xn, wqT + sqo, wkT + sqo, wvT + sqo,
                                                    qb, kb, vt, tab);
    attn_k<<<dim3(S_LEN/64, B_SZ*NH), 256, 0, stream>>>(qb, kb, vt, ob, spp);
    gemm_k<1,2,2,4><<<dim3(DIM/64, R/64), 256, 0, stream>>>(ob, woT + sqo, h, nullptr, DIM, DIM);
    rmsnorm_k<<<R, 256, 0, stream>>>(h, fnw + l*DIM, xn);
    gemm_ffn13_k<<<dim3(HID/64, R/64), 256, 0, stream>>>(xn, w1T + sff, w3T + sff, g);
    gemm_k<1,2,2,4><<<dim3(DIM/64, R/64), 256, 0, stream>>>(g, w2T + sff, h, nullptr, DIM, HID);
  }
  rmsnorm_last_k<<<B_SZ, 256, 0, stream>>>(h, finw, xfin);
  hipMemsetAsync(d_out, 0, (size_t)out_size * sizeof(float), stream);
  outproj_k<<<dim3(NVOCAB/256, 2), 256, 0, stream>>>(xfin, outw, (float*)d_out);
}